// Round 4
// baseline (698.053 us; speedup 1.0000x reference)
//
#include <hip/hip_runtime.h>
#include <hip/hip_cooperative_groups.h>
#include <math.h>

namespace cg = cooperative_groups;

typedef unsigned short u16;
typedef __attribute__((ext_vector_type(8))) short short8;
typedef __attribute__((ext_vector_type(4))) float f32x4;
typedef __attribute__((ext_vector_type(4))) unsigned short u16x4;
typedef __attribute__((ext_vector_type(8))) unsigned short u16x8;

#define N_TOK 2048
#define DIM 1024
#define OUT_ELEMS 2097152   // N_TOK * DIM

#define GLDS16(gp, lp) __builtin_amdgcn_global_load_lds( \
    (const __attribute__((address_space(1))) unsigned int*)(gp), \
    (__attribute__((address_space(3))) unsigned int*)(lp), 16, 0, 0)

__device__ __forceinline__ u16 f2bf(float f) {
    union { float f; unsigned u; } v; v.f = f;
    unsigned r = (v.u + 0x7FFFu + ((v.u >> 16) & 1u)) >> 16;
    return (u16)r;
}
__device__ __forceinline__ float bf2f(u16 h) {
    union { unsigned u; float f; } v; v.u = ((unsigned)h) << 16;
    return v.f;
}

// ---- cvt of one 8-row k-chunk: fp32 [8][1024] -> bf16 W'[n][8k] (16KB) ----
__device__ __forceinline__ void cvt_chunk(const float* __restrict__ src,
                                          u16* __restrict__ dst, int chunk,
                                          char* smem, int t) {
    float* tile = (float*)smem;                          // [8][1024] f32 = 32KB
    const char* gsrc = (const char*)(src + (size_t)chunk * 8192);
    u16* dchunk = dst + (size_t)chunk * 8192;            // 16KB contiguous out
    int w = t >> 6, l = t & 63;
#pragma unroll
    for (int j = 0; j < 8; j++) {
        int idx = w * 8 + j;                             // 1KB unit, 0..31
        GLDS16(gsrc + idx * 1024 + l * 16, smem + idx * 1024);
    }
    __syncthreads();
    int n0 = (t & 63) * 4 + (t >> 6) * 256;              // 4 consecutive n per thread
    f32x4 v[8];
#pragma unroll
    for (int k = 0; k < 8; k++)
        v[k] = *(const f32x4*)(tile + k * 1024 + n0);    // bank = n%32: conflict-free
#pragma unroll
    for (int i = 0; i < 4; i++) {
        u16x8 o;
#pragma unroll
        for (int k = 0; k < 8; k++) o[k] = f2bf(v[k][i]);
        *(u16x8*)(dchunk + (size_t)(n0 + i) * 8) = o;    // 16B aligned, coalesced
    }
}

__device__ __forceinline__ void cvt_gu_job(int j, const float* wg, const float* wu,
                                           const float* wsg, const float* wsu,
                                           u16* wgt, u16* wut, u16* wsgt, u16* wsut,
                                           char* smem, int t) {
    int mat = j >> 7, chunk = j & 127;
    const float* src; u16* dst;
    if      (mat <  8) { src = wg + (size_t)mat * 1048576;       dst = wgt + (size_t)mat * 1048576; }
    else if (mat < 16) { src = wu + (size_t)(mat - 8) * 1048576; dst = wut + (size_t)(mat - 8) * 1048576; }
    else if (mat == 16){ src = wsg; dst = wsgt; }
    else               { src = wsu; dst = wsut; }
    cvt_chunk(src, dst, chunk, smem, t);
}

__device__ __forceinline__ void cvt_d_job(int j, const float* wd, const float* wsd,
                                          u16* wdt, u16* wsdt, char* smem, int t) {
    int mat = j >> 7, chunk = j & 127;
    const float* src = (mat < 8) ? (wd + (size_t)mat * 1048576) : wsd;
    u16* dst = (mat < 8) ? (wdt + (size_t)mat * 1048576) : wsdt;
    cvt_chunk(src, dst, chunk, smem, t);
}

// ---- router: block-job b handles tokens 4b..4b+3, one per wave ------------
__device__ __forceinline__ void router_job(int b, const float* x, const float* wgate,
                                           u16* xb, int* tidx, float* tw,
                                           float* Pp, int* Cp, int* tlist,
                                           int* curs, char* smem, int t) {
    float* sP = (float*)smem;
    int*   sC = (int*)(smem + 64);
    if (t < 8) { sP[t] = 0.f; sC[t] = 0; }
    if (b == 0 && t < 16) curs[t] = 0;                   // consumed next phase
    __syncthreads();
    int wave = t >> 6;
    int lane = t & 63;
    int n = b * 4 + wave;
    const float* xr = x + (size_t)n * DIM;
    u16* xbr = xb + (size_t)n * DIM;
    float acc[8] = {0.f,0.f,0.f,0.f,0.f,0.f,0.f,0.f};
#pragma unroll
    for (int i = 0; i < 16; i++) {
        int d = lane + i * 64;
        float xv = xr[d];
        xbr[d] = f2bf(xv);
        const float* wr = wgate + d * 8;
#pragma unroll
        for (int e = 0; e < 8; e++) acc[e] += xv * wr[e];
    }
#pragma unroll
    for (int off = 32; off; off >>= 1) {
#pragma unroll
        for (int e = 0; e < 8; e++) acc[e] += __shfl_xor(acc[e], off);
    }
    if (lane == 0) {
        tlist[4096 + n] = n;                             // shared-expert token list
        float mx = acc[0];
#pragma unroll
        for (int e = 1; e < 8; e++) mx = fmaxf(mx, acc[e]);
        float p[8], s = 0.f;
#pragma unroll
        for (int e = 0; e < 8; e++) { p[e] = expf(acc[e] - mx); s += p[e]; }
        float inv = 1.f / s;
#pragma unroll
        for (int e = 0; e < 8; e++) atomicAdd(&sP[e], p[e] * inv);
        int i0 = 0; float b0 = acc[0];
#pragma unroll
        for (int e = 1; e < 8; e++) if (acc[e] > b0) { b0 = acc[e]; i0 = e; }
        int i1 = -1; float b1 = -3.4e38f;
#pragma unroll
        for (int e = 0; e < 8; e++) if (e != i0 && acc[e] > b1) { b1 = acc[e]; i1 = e; }
        float w0 = 1.f / (1.f + expf(b1 - b0));
        tidx[n * 2] = i0; tidx[n * 2 + 1] = i1;
        tw[n * 2] = w0;   tw[n * 2 + 1] = 1.f - w0;
        atomicAdd(&sC[i0], 1);
        atomicAdd(&sC[i1], 1);
    }
    __syncthreads();
    if (t < 8) { Pp[b * 8 + t] = sP[t]; Cp[b * 8 + t] = sC[t]; }
}

// ---- scatter: reduce partials, aux loss, offs, slot assignment -------------
__device__ __forceinline__ void scatter_job(int bid, const int* tidx, const float* Pp,
                                            const int* Cp, int* curs, int* tlist,
                                            int* slots, float* out, int* counts,
                                            int* offs, char* smem, int t) {
    int*   s_off = (int*)smem;               // 32B
    int*   sCnt  = (int*)(smem + 32);        // 32B
    float* sPs   = (float*)(smem + 64);      // 32B
    int*   redC  = (int*)(smem + 128);       // 1KB
    float* redP  = (float*)(smem + 1152);    // 1KB
    int e = t & 7, g = t >> 3;
    int cs = 0; float ps = 0.f;
#pragma unroll
    for (int j = 0; j < 16; j++) {
        int b = g + j * 32;
        cs += Cp[b * 8 + e];
        ps += Pp[b * 8 + e];
    }
    redC[t] = cs; redP[t] = ps;
    __syncthreads();
    if (t < 8) {
        int c = 0; float p = 0.f;
        for (int g2 = 0; g2 < 32; g2++) { c += redC[g2 * 8 + t]; p += redP[g2 * 8 + t]; }
        sCnt[t] = c; sPs[t] = p;
    }
    __syncthreads();
    if (t == 0) {
        int o = 0;
        for (int e2 = 0; e2 < 8; e2++) { s_off[e2] = o; o += sCnt[e2]; }
    }
    __syncthreads();
    if (bid == 0 && t == 0) {
        float aux = 0.f;
        for (int e2 = 0; e2 < 8; e2++) {
            aux += (float)sCnt[e2] * sPs[e2];
            offs[e2] = s_off[e2]; counts[e2] = sCnt[e2];
        }
        out[OUT_ELEMS] = 8.f * aux / ((float)N_TOK * (float)N_TOK);
        offs[8] = 4096; counts[8] = 2048;
    }
    int n = bid * 256 + t;
    if (n < N_TOK) {
#pragma unroll
        for (int k = 0; k < 2; k++) {
            int ee = tidx[n * 2 + k];
            int p = atomicAdd(&curs[ee], 1);
            int sl = s_off[ee] + p;
            tlist[sl] = n;
            slots[n * 2 + k] = sl;
        }
    }
}

// ---- gemm job mapping: shared-expert tiles first, then routed mt-major -----
// All ~384 ACTIVE tiles land in jj < ~512 so they start in scheduling round 1.
__device__ __forceinline__ void gemm_map(int jj, int& job, int& mt, int& nt) {
    if (jj < 128) { job = 8; mt = jj >> 3; nt = jj & 7; }
    else {
        int r = jj - 128;
        mt = r >> 6;                  // 0..15
        int rem = r & 63;
        job = rem >> 3;               // 0..7
        nt = rem & 7;
    }
}

// ---- GEMM1 job: gathered X @ [Wg|Wu], fused silu*u -> H bf16 (dbuf) --------
__device__ __forceinline__ void gemm1_job(
    int jj, const u16* __restrict__ xb, const u16* __restrict__ wgt,
    const u16* __restrict__ wut, const u16* __restrict__ wsgt,
    const u16* __restrict__ wsut, const int* __restrict__ tlist,
    const int* __restrict__ counts, const int* __restrict__ offs,
    u16* __restrict__ H, char* smem, int t) {
    int job, mt, nt; gemm_map(jj, job, mt, nt);
    int jcnt = counts[job];
    int m0 = mt << 7;
    if (m0 >= jcnt) return;                              // block-uniform
    int joff = offs[job];
    int n0 = nt << 7;
    const u16* Bg = (job < 8) ? (wgt + (size_t)job * 1048576) : wsgt;
    const u16* Bu = (job < 8) ? (wut + (size_t)job * 1048576) : wsut;

    int wave = t >> 6, lane = t & 63;
    int ch = (lane & 3) * 8;
    int r0 = (wave * 2 + 0) * 16 + (lane >> 2);
    int r1 = (wave * 2 + 1) * 16 + (lane >> 2);
    int tok0 = tlist[joff + m0 + r0];
    int tok1 = tlist[joff + m0 + r1];
    const u16* a0 = xb + (size_t)tok0 * 1024 + ch;
    const u16* a1 = xb + (size_t)tok1 * 1024 + ch;
    const u16* gB = Bg + (size_t)wave * 8192 + (size_t)(n0 + lane) * 8;
    const u16* uB = Bu + (size_t)wave * 8192 + (size_t)(n0 + lane) * 8;

    int wm = (wave >> 1) << 6, wn = (wave & 1) << 6;
    int quad = lane >> 4, lr = lane & 15;

    f32x4 accg[4][4], accu[4][4];
    f32x4 zz = {0.f, 0.f, 0.f, 0.f};
#pragma unroll
    for (int i = 0; i < 4; i++)
#pragma unroll
        for (int j = 0; j < 4; j++) { accg[i][j] = zz; accu[i][j] = zz; }

#define STAGE1(b_, s_) do { \
        char* bb = smem + (b_) * 24576; \
        u16* As_  = (u16*)bb; \
        u16* Bgs_ = (u16*)(bb + 8192); \
        u16* Bus_ = (u16*)(bb + 16384); \
        int k0_ = (s_) * 32; \
        size_t koff_ = (size_t)k0_ * 1024; \
        GLDS16(a0 + k0_, As_ + (wave * 2 + 0) * 512); \
        GLDS16(a1 + k0_, As_ + (wave * 2 + 1) * 512); \
        GLDS16(gB + koff_,       Bgs_ + wave * 1024); \
        GLDS16(gB + koff_ + 512, Bgs_ + wave * 1024 + 512); \
        GLDS16(uB + koff_,       Bus_ + wave * 1024); \
        GLDS16(uB + koff_ + 512, Bus_ + wave * 1024 + 512); \
    } while (0)

    STAGE1(0, 0);
    __syncthreads();
    for (int s = 0; s < 32; s++) {
        int cur = s & 1;
        if (s < 31) STAGE1(cur ^ 1, s + 1);
        const char* cb = smem + cur * 24576;
        const u16* Asr = (const u16*)cb;
        const u16* Bgr = (const u16*)(cb + 8192);
        const u16* Bur = (const u16*)(cb + 16384);
        short8 af[4], bgf[4], buf[4];
#pragma unroll
        for (int i = 0; i < 4; i++) {
            int nrow = wn + i * 16 + lr;
            af[i]  = *(const short8*)(Asr + (wm + i * 16 + lr) * 32 + quad * 8);
            bgf[i] = *(const short8*)(Bgr + quad * 1024 + nrow * 8);
            buf[i] = *(const short8*)(Bur + quad * 1024 + nrow * 8);
        }
#pragma unroll
        for (int mi = 0; mi < 4; mi++)
#pragma unroll
            for (int ni = 0; ni < 4; ni++) {
                accg[mi][ni] = __builtin_amdgcn_mfma_f32_16x16x32_bf16(af[mi], bgf[ni], accg[mi][ni], 0, 0, 0);
                accu[mi][ni] = __builtin_amdgcn_mfma_f32_16x16x32_bf16(af[mi], buf[ni], accu[mi][ni], 0, 0, 0);
            }
        __syncthreads();
    }
#undef STAGE1
#pragma unroll
    for (int mi = 0; mi < 4; mi++) {
        int rowb = m0 + wm + mi * 16 + quad * 4;
#pragma unroll
        for (int rr = 0; rr < 4; rr++) {
            int row = rowb + rr;
            if (row < jcnt) {
                size_t base = (size_t)(joff + row) * 1024 + n0 + wn;
#pragma unroll
                for (int ni = 0; ni < 4; ni++) {
                    float g = accg[mi][ni][rr];
                    float u = accu[mi][ni][rr];
                    float h = (g / (1.f + expf(-g))) * u;
                    H[base + ni * 16 + lr] = f2bf(h);
                }
            }
        }
    }
}

// ---- GEMM2 job: H @ Wd -> Y bf16 (dbuf) ------------------------------------
__device__ __forceinline__ void gemm2_job(
    int jj, const u16* __restrict__ H, const u16* __restrict__ wdt,
    const u16* __restrict__ wsdt, const int* __restrict__ counts,
    const int* __restrict__ offs, u16* __restrict__ Y, char* smem, int t) {
    int job, mt, nt; gemm_map(jj, job, mt, nt);
    int jcnt = counts[job];
    int m0 = mt << 7;
    if (m0 >= jcnt) return;
    int joff = offs[job];
    int n0 = nt << 7;
    const u16* Bt = (job < 8) ? (wdt + (size_t)job * 1048576) : wsdt;

    int wave = t >> 6, lane = t & 63;
    int ch = (lane & 3) * 8;
    int r0 = (wave * 2 + 0) * 16 + (lane >> 2);
    int r1 = (wave * 2 + 1) * 16 + (lane >> 2);
    const u16* a0 = H + (size_t)(joff + m0 + r0) * 1024 + ch;
    const u16* a1 = H + (size_t)(joff + m0 + r1) * 1024 + ch;
    const u16* bB = Bt + (size_t)wave * 8192 + (size_t)(n0 + lane) * 8;

    int wm = (wave >> 1) << 6, wn = (wave & 1) << 6;
    int quad = lane >> 4, lr = lane & 15;

    f32x4 acc[4][4];
    f32x4 zz = {0.f, 0.f, 0.f, 0.f};
#pragma unroll
    for (int i = 0; i < 4; i++)
#pragma unroll
        for (int j = 0; j < 4; j++) acc[i][j] = zz;

#define STAGE2(b_, s_) do { \
        char* bb = smem + (b_) * 16384; \
        u16* As_ = (u16*)bb; \
        u16* Bs_ = (u16*)(bb + 8192); \
        int k0_ = (s_) * 32; \
        size_t koff_ = (size_t)k0_ * 1024; \
        GLDS16(a0 + k0_, As_ + (wave * 2 + 0) * 512); \
        GLDS16(a1 + k0_, As_ + (wave * 2 + 1) * 512); \
        GLDS16(bB + koff_,       Bs_ + wave * 1024); \
        GLDS16(bB + koff_ + 512, Bs_ + wave * 1024 + 512); \
    } while (0)

    STAGE2(0, 0);
    __syncthreads();
    for (int s = 0; s < 32; s++) {
        int cur = s & 1;
        if (s < 31) STAGE2(cur ^ 1, s + 1);
        const char* cb = smem + cur * 16384;
        const u16* Asr = (const u16*)cb;
        const u16* Bsr = (const u16*)(cb + 8192);
        short8 af[4], bf[4];
#pragma unroll
        for (int i = 0; i < 4; i++) {
            af[i] = *(const short8*)(Asr + (wm + i * 16 + lr) * 32 + quad * 8);
            bf[i] = *(const short8*)(Bsr + quad * 1024 + (wn + i * 16 + lr) * 8);
        }
#pragma unroll
        for (int mi = 0; mi < 4; mi++)
#pragma unroll
            for (int ni = 0; ni < 4; ni++)
                acc[mi][ni] = __builtin_amdgcn_mfma_f32_16x16x32_bf16(af[mi], bf[ni], acc[mi][ni], 0, 0, 0);
        __syncthreads();
    }
#undef STAGE2
#pragma unroll
    for (int mi = 0; mi < 4; mi++) {
        int rowb = m0 + wm + mi * 16 + quad * 4;
#pragma unroll
        for (int rr = 0; rr < 4; rr++) {
            int row = rowb + rr;
            if (row < jcnt) {
                u16* yrow = Y + (size_t)(joff + row) * 1024 + n0 + wn;
#pragma unroll
                for (int ni = 0; ni < 4; ni++)
                    yrow[ni * 16 + lr] = f2bf(acc[mi][ni][rr]);
            }
        }
    }
}

// ---- combine job: out[n] = w0*Y[s0] + w1*Y[s1] + Y[4096+n] -----------------
__device__ __forceinline__ void combine_job(int n, const u16* __restrict__ Y,
                                            const int* __restrict__ slots,
                                            const float* __restrict__ tw,
                                            float* __restrict__ out, int t) {
    int s0 = slots[n * 2], s1 = slots[n * 2 + 1];
    float w0 = tw[n * 2], w1 = tw[n * 2 + 1];
    u16x4 y0 = ((const u16x4*)(Y + (size_t)s0 * 1024))[t];
    u16x4 y1 = ((const u16x4*)(Y + (size_t)s1 * 1024))[t];
    u16x4 ys = ((const u16x4*)(Y + (size_t)(4096 + n) * 1024))[t];
    f32x4 r;
    r.x = w0 * bf2f(y0.x) + w1 * bf2f(y1.x) + bf2f(ys.x);
    r.y = w0 * bf2f(y0.y) + w1 * bf2f(y1.y) + bf2f(ys.y);
    r.z = w0 * bf2f(y0.z) + w1 * bf2f(y1.z) + bf2f(ys.z);
    r.w = w0 * bf2f(y0.w) + w1 * bf2f(y1.w) + bf2f(ys.w);
    ((f32x4*)(out + (size_t)n * 1024))[t] = r;
}

// ================= cooperative mega-kernel: one launch, 5 phases ============
__global__ __launch_bounds__(256, 3)
void k_mega(const float* x, const float* wgate, const float* wg, const float* wu,
            const float* wd, const float* wsg, const float* wsu, const float* wsd,
            float* out, u16* xb, u16* wgt, u16* wut, u16* wdt, u16* wsgt,
            u16* wsut, u16* wsdt, u16* H, u16* Y, int* tidx, float* tw,
            int* tlist, int* slots, int* counts, int* offs, int* curs,
            float* Pp, int* Cp) {
    cg::grid_group grid = cg::this_grid();
    __shared__ __attribute__((aligned(128))) char smem[49152];
    int bid = blockIdx.x;
    int t = threadIdx.x;
    const int NB = (int)gridDim.x;

    // -- Phase A: router (jobs 0..511) then cvt gate/up (512..2815) ----------
    for (int j = bid; j < 2816; j += NB) {
        __syncthreads();                                 // LDS reuse guard
        if (j < 512) router_job(j, x, wgate, xb, tidx, tw, Pp, Cp, tlist, curs, smem, t);
        else         cvt_gu_job(j - 512, wg, wu, wsg, wsu, wgt, wut, wsgt, wsut, smem, t);
    }
    grid.sync();
    // -- Phase B: scatter (8 blocks) -----------------------------------------
    if (bid < 8)
        scatter_job(bid, tidx, Pp, Cp, curs, tlist, slots, out, counts, offs, smem, t);
    grid.sync();
    // -- Phase C: gemm1 (jobs 0..1151, active-first) + cvt down (1152..2303) -
    for (int j = bid; j < 2304; j += NB) {
        __syncthreads();
        if (j < 1152) gemm1_job(j, xb, wgt, wut, wsgt, wsut, tlist, counts, offs, H, smem, t);
        else          cvt_d_job(j - 1152, wd, wsd, wdt, wsdt, smem, t);
    }
    grid.sync();
    // -- Phase D: gemm2 ------------------------------------------------------
    for (int j = bid; j < 1152; j += NB) {
        __syncthreads();
        gemm2_job(j, H, wdt, wsdt, counts, offs, Y, smem, t);
    }
    grid.sync();
    // -- Phase E: combine ----------------------------------------------------
    for (int n = bid; n < 2048; n += NB)
        combine_job(n, Y, slots, tw, out, t);
}

// ================= fallback drivers (5 launches, same device code) ==========
__global__ __launch_bounds__(256)
void k_front(const float* __restrict__ wg, const float* __restrict__ wu,
             const float* __restrict__ wsg, const float* __restrict__ wsu,
             u16* __restrict__ wgt, u16* __restrict__ wut,
             u16* __restrict__ wsgt, u16* __restrict__ wsut,
             const float* __restrict__ x, const float* __restrict__ wgate,
             u16* __restrict__ xb, int* __restrict__ tidx, float* __restrict__ tw,
             float* __restrict__ Pp, int* __restrict__ Cp,
             int* __restrict__ tlist, int* __restrict__ curs) {
    __shared__ __attribute__((aligned(128))) char smem[32768];
    int bx = blockIdx.x, t = threadIdx.x;
    if (bx < 512) router_job(bx, x, wgate, xb, tidx, tw, Pp, Cp, tlist, curs, smem, t);
    else          cvt_gu_job(bx - 512, wg, wu, wsg, wsu, wgt, wut, wsgt, wsut, smem, t);
}

__global__ void k_scatter(const int* __restrict__ tidx, const float* __restrict__ Pp,
                          const int* __restrict__ Cp, int* __restrict__ curs,
                          int* __restrict__ tlist, int* __restrict__ slots,
                          float* __restrict__ out, int* __restrict__ counts,
                          int* __restrict__ offs) {
    __shared__ __attribute__((aligned(128))) char smem[4096];
    scatter_job(blockIdx.x, tidx, Pp, Cp, curs, tlist, slots, out, counts, offs,
                smem, threadIdx.x);
}

__global__ __launch_bounds__(256, 2)
void k_gemm1(const u16* __restrict__ xb, const u16* __restrict__ wgt,
             const u16* __restrict__ wut, const u16* __restrict__ wsgt,
             const u16* __restrict__ wsut, const int* __restrict__ tlist,
             const int* __restrict__ counts, const int* __restrict__ offs,
             u16* __restrict__ H,
             const float* __restrict__ wd, const float* __restrict__ wsd,
             u16* __restrict__ wdt, u16* __restrict__ wsdt) {
    __shared__ __attribute__((aligned(128))) char smem[49152];
    int bx = blockIdx.x, t = threadIdx.x;
    if (bx < 1152) gemm1_job(bx, xb, wgt, wut, wsgt, wsut, tlist, counts, offs, H, smem, t);
    else           cvt_d_job(bx - 1152, wd, wsd, wdt, wsdt, smem, t);
}

__global__ __launch_bounds__(256, 2)
void k_gemm2(const u16* __restrict__ H, const u16* __restrict__ wdt,
             const u16* __restrict__ wsdt, const int* __restrict__ counts,
             const int* __restrict__ offs, u16* __restrict__ Y) {
    __shared__ __attribute__((aligned(128))) char smem[32768];
    gemm2_job(blockIdx.x, H, wdt, wsdt, counts, offs, Y, smem, threadIdx.x);
}

__global__ void k_combine(const u16* __restrict__ Y, const int* __restrict__ slots,
                          const float* __restrict__ tw, float* __restrict__ out) {
    combine_job(blockIdx.x, Y, slots, tw, out, threadIdx.x);
}

extern "C" void kernel_launch(void* const* d_in, const int* in_sizes, int n_in,
                              void* d_out, int out_size, void* d_ws, size_t ws_size,
                              hipStream_t stream) {
    const float* x     = (const float*)d_in[0];
    const float* wgate = (const float*)d_in[1];
    const float* wg    = (const float*)d_in[2];
    const float* wu    = (const float*)d_in[3];
    const float* wd    = (const float*)d_in[4];
    const float* wsg   = (const float*)d_in[5];
    const float* wsu   = (const float*)d_in[6];
    const float* wsd   = (const float*)d_in[7];
    float* out = (float*)d_out;

    char* ws = (char*)d_ws;
    u16*   xb    = (u16*)(ws + 0);           // 4 MB
    u16*   wgt   = (u16*)(ws + 4194304);     // 16 MB
    u16*   wut   = (u16*)(ws + 20971520);    // 16 MB
    u16*   wdt   = (u16*)(ws + 37748736);    // 16 MB
    u16*   wsgt  = (u16*)(ws + 54525952);    // 2 MB
    u16*   wsut  = (u16*)(ws + 56623104);    // 2 MB
    u16*   wsdt  = (u16*)(ws + 58720256);    // 2 MB
    u16*   H     = (u16*)(ws + 60817408);    // 12.58 MB (6144 rows)
    // Y (bf16) overlays wgt (dead after gemm1; gemm2 runs strictly after)
    u16*   Y     = (u16*)(ws + 4194304);
    int*   tidx  = (int*)(ws + 73400320);
    float* tw    = (float*)(ws + 73416704);
    int*   tlist = (int*)(ws + 73433088);
    int*   slots = (int*)(ws + 73457664);
    int*   counts= (int*)(ws + 73474048);
    int*   offs  = (int*)(ws + 73474112);
    int*   curs  = (int*)(ws + 73474176);
    float* Pp    = (float*)(ws + 73474304);  // 512*8 f32 = 16 KB
    int*   Cp    = (int*)(ws + 73490688);    // 512*8 i32 = 16 KB

    void* args[] = { &x, &wgate, &wg, &wu, &wd, &wsg, &wsu, &wsd, &out,
                     &xb, &wgt, &wut, &wdt, &wsgt, &wsut, &wsdt, &H, &Y,
                     &tidx, &tw, &tlist, &slots, &counts, &offs, &curs,
                     &Pp, &Cp };
    hipError_t err = hipLaunchCooperativeKernel((const void*)k_mega, dim3(768),
                                                dim3(256), args, 0, stream);
    if (err == hipSuccess) return;
    (void)hipGetLastError();                 // clear sticky error, take fallback

    k_front<<<2816, 256, 0, stream>>>(wg, wu, wsg, wsu, wgt, wut, wsgt, wsut,
                                      x, wgate, xb, tidx, tw, Pp, Cp, tlist, curs);
    k_scatter<<<8, 256, 0, stream>>>(tidx, Pp, Cp, curs, tlist, slots,
                                     out, counts, offs);
    k_gemm1<<<2304, 256, 0, stream>>>(xb, wgt, wut, wsgt, wsut, tlist, counts, offs,
                                      H, wd, wsd, wdt, wsdt);
    k_gemm2<<<1152, 256, 0, stream>>>(H, wdt, wsdt, counts, offs, Y);
    k_combine<<<2048, 256, 0, stream>>>(Y, slots, tw, out);
}

// Round 6
// 239.884 us; speedup vs baseline: 2.9100x; 2.9100x over previous
//
#include <hip/hip_runtime.h>
#include <math.h>

typedef unsigned short u16;
typedef __attribute__((ext_vector_type(8))) short short8;
typedef __attribute__((ext_vector_type(4))) float f32x4;
typedef __attribute__((ext_vector_type(4))) unsigned short u16x4;
typedef __attribute__((ext_vector_type(8))) unsigned short u16x8;

#define N_TOK 2048
#define DIM 1024
#define OUT_ELEMS 2097152   // N_TOK * DIM

#define GLDS16(gp, lp) __builtin_amdgcn_global_load_lds( \
    (const __attribute__((address_space(1))) unsigned int*)(gp), \
    (__attribute__((address_space(3))) unsigned int*)(lp), 16, 0, 0)

__device__ __forceinline__ u16 f2bf(float f) {
    union { float f; unsigned u; } v; v.f = f;
    unsigned r = (v.u + 0x7FFFu + ((v.u >> 16) & 1u)) >> 16;
    return (u16)r;
}
__device__ __forceinline__ float bf2f(u16 h) {
    union { unsigned u; float f; } v; v.u = ((unsigned)h) << 16;
    return v.f;
}

// ---- cvt of one 8-row k-chunk: fp32 [8][1024] -> bf16 W'[n][8k] (16KB) ----
__device__ __forceinline__ void cvt_chunk(const float* __restrict__ src,
                                          u16* __restrict__ dst, int chunk,
                                          char* smem, int t) {
    float* tile = (float*)smem;                          // [8][1024] f32 = 32KB
    const char* gsrc = (const char*)(src + (size_t)chunk * 8192);
    u16* dchunk = dst + (size_t)chunk * 8192;            // 16KB contiguous out
    int w = t >> 6, l = t & 63;
#pragma unroll
    for (int j = 0; j < 8; j++) {
        int idx = w * 8 + j;                             // 1KB unit, 0..31
        GLDS16(gsrc + idx * 1024 + l * 16, smem + idx * 1024);
    }
    __syncthreads();
    int n0 = (t & 63) * 4 + (t >> 6) * 256;              // 4 consecutive n per thread
    f32x4 v[8];
#pragma unroll
    for (int k = 0; k < 8; k++)
        v[k] = *(const f32x4*)(tile + k * 1024 + n0);    // bank = n%32: conflict-free
#pragma unroll
    for (int i = 0; i < 4; i++) {
        u16x8 o;
#pragma unroll
        for (int k = 0; k < 8; k++) o[k] = f2bf(v[k][i]);
        *(u16x8*)(dchunk + (size_t)(n0 + i) * 8) = o;    // 16B aligned, coalesced
    }
}

__device__ __forceinline__ void cvt_gu_job(int j, const float* wg, const float* wu,
                                           const float* wsg, const float* wsu,
                                           u16* wgt, u16* wut, u16* wsgt, u16* wsut,
                                           char* smem, int t) {
    int mat = j >> 7, chunk = j & 127;
    const float* src; u16* dst;
    if      (mat <  8) { src = wg + (size_t)mat * 1048576;       dst = wgt + (size_t)mat * 1048576; }
    else if (mat < 16) { src = wu + (size_t)(mat - 8) * 1048576; dst = wut + (size_t)(mat - 8) * 1048576; }
    else if (mat == 16){ src = wsg; dst = wsgt; }
    else               { src = wsu; dst = wsut; }
    cvt_chunk(src, dst, chunk, smem, t);
}

__device__ __forceinline__ void cvt_d_job(int j, const float* wd, const float* wsd,
                                          u16* wdt, u16* wsdt, char* smem, int t) {
    int mat = j >> 7, chunk = j & 127;
    const float* src = (mat < 8) ? (wd + (size_t)mat * 1048576) : wsd;
    u16* dst = (mat < 8) ? (wdt + (size_t)mat * 1048576) : wsdt;
    cvt_chunk(src, dst, chunk, smem, t);
}

// ---- router: block-job b handles tokens 4b..4b+3, one per wave ------------
__device__ __forceinline__ void router_job(int b, const float* x, const float* wgate,
                                           u16* xb, int* tidx, float* tw,
                                           float* Pp, int* Cp, int* tlist,
                                           int* curs, char* smem, int t) {
    float* sP = (float*)smem;
    int*   sC = (int*)(smem + 64);
    if (t < 8) { sP[t] = 0.f; sC[t] = 0; }
    if (b == 0 && t < 16) curs[t] = 0;                   // consumed next launch
    __syncthreads();
    int wave = t >> 6;
    int lane = t & 63;
    int n = b * 4 + wave;
    const float* xr = x + (size_t)n * DIM;
    u16* xbr = xb + (size_t)n * DIM;
    float acc[8] = {0.f,0.f,0.f,0.f,0.f,0.f,0.f,0.f};
#pragma unroll
    for (int i = 0; i < 16; i++) {
        int d = lane + i * 64;
        float xv = xr[d];
        xbr[d] = f2bf(xv);
        const float* wr = wgate + d * 8;
#pragma unroll
        for (int e = 0; e < 8; e++) acc[e] += xv * wr[e];
    }
#pragma unroll
    for (int off = 32; off; off >>= 1) {
#pragma unroll
        for (int e = 0; e < 8; e++) acc[e] += __shfl_xor(acc[e], off);
    }
    if (lane == 0) {
        tlist[4096 + n] = n;                             // shared-expert token list
        float mx = acc[0];
#pragma unroll
        for (int e = 1; e < 8; e++) mx = fmaxf(mx, acc[e]);
        float p[8], s = 0.f;
#pragma unroll
        for (int e = 0; e < 8; e++) { p[e] = expf(acc[e] - mx); s += p[e]; }
        float inv = 1.f / s;
#pragma unroll
        for (int e = 0; e < 8; e++) atomicAdd(&sP[e], p[e] * inv);
        int i0 = 0; float b0 = acc[0];
#pragma unroll
        for (int e = 1; e < 8; e++) if (acc[e] > b0) { b0 = acc[e]; i0 = e; }
        int i1 = -1; float b1 = -3.4e38f;
#pragma unroll
        for (int e = 0; e < 8; e++) if (e != i0 && acc[e] > b1) { b1 = acc[e]; i1 = e; }
        float w0 = 1.f / (1.f + expf(b1 - b0));
        tidx[n * 2] = i0; tidx[n * 2 + 1] = i1;
        tw[n * 2] = w0;   tw[n * 2 + 1] = 1.f - w0;
        atomicAdd(&sC[i0], 1);
        atomicAdd(&sC[i1], 1);
    }
    __syncthreads();
    if (t < 8) { Pp[b * 8 + t] = sP[t]; Cp[b * 8 + t] = sC[t]; }
}

// ---- scatter: reduce partials, aux loss, offs, slot assignment -------------
__device__ __forceinline__ void scatter_job(int bid, const int* tidx, const float* Pp,
                                            const int* Cp, int* curs, int* tlist,
                                            int* slots, float* out, int* counts,
                                            int* offs, char* smem, int t) {
    int*   s_off = (int*)smem;               // 32B
    int*   sCnt  = (int*)(smem + 32);        // 32B
    float* sPs   = (float*)(smem + 64);      // 32B
    int*   redC  = (int*)(smem + 128);       // 1KB
    float* redP  = (float*)(smem + 1152);    // 1KB
    int e = t & 7, g = t >> 3;
    int cs = 0; float ps = 0.f;
#pragma unroll
    for (int j = 0; j < 16; j++) {
        int b = g + j * 32;
        cs += Cp[b * 8 + e];
        ps += Pp[b * 8 + e];
    }
    redC[t] = cs; redP[t] = ps;
    __syncthreads();
    if (t < 8) {
        int c = 0; float p = 0.f;
        for (int g2 = 0; g2 < 32; g2++) { c += redC[g2 * 8 + t]; p += redP[g2 * 8 + t]; }
        sCnt[t] = c; sPs[t] = p;
    }
    __syncthreads();
    if (t == 0) {
        int o = 0;
        for (int e2 = 0; e2 < 8; e2++) { s_off[e2] = o; o += sCnt[e2]; }
    }
    __syncthreads();
    if (bid == 0 && t == 0) {
        float aux = 0.f;
        for (int e2 = 0; e2 < 8; e2++) {
            aux += (float)sCnt[e2] * sPs[e2];
            offs[e2] = s_off[e2]; counts[e2] = sCnt[e2];
        }
        out[OUT_ELEMS] = 8.f * aux / ((float)N_TOK * (float)N_TOK);
        offs[8] = 4096; counts[8] = 2048;
    }
    int n = bid * 256 + t;
    if (n < N_TOK) {
#pragma unroll
        for (int k = 0; k < 2; k++) {
            int ee = tidx[n * 2 + k];
            int p = atomicAdd(&curs[ee], 1);
            int sl = s_off[ee] + p;
            tlist[sl] = n;
            slots[n * 2 + k] = sl;
        }
    }
}

// ---- gemm job mapping: shared-expert tiles first, then routed mt-major -----
// All ~384 ACTIVE tiles land at low jj so they start in scheduling round 1.
__device__ __forceinline__ void gemm_map(int jj, int& job, int& mt, int& nt) {
    if (jj < 128) { job = 8; mt = jj >> 3; nt = jj & 7; }
    else {
        int r = jj - 128;
        mt = r >> 6;                  // 0..15
        int rem = r & 63;
        job = rem >> 3;               // 0..7
        nt = rem & 7;
    }
}

// ---- GEMM1 job: gathered X @ [Wg|Wu], fused silu*u -> H bf16 (dbuf) --------
__device__ __forceinline__ void gemm1_job(
    int jj, const u16* __restrict__ xb, const u16* __restrict__ wgt,
    const u16* __restrict__ wut, const u16* __restrict__ wsgt,
    const u16* __restrict__ wsut, const int* __restrict__ tlist,
    const int* __restrict__ counts, const int* __restrict__ offs,
    u16* __restrict__ H, char* smem, int t) {
    int job, mt, nt; gemm_map(jj, job, mt, nt);
    int jcnt = counts[job];
    int m0 = mt << 7;
    if (m0 >= jcnt) return;                              // block-uniform
    int joff = offs[job];
    int n0 = nt << 7;
    const u16* Bg = (job < 8) ? (wgt + (size_t)job * 1048576) : wsgt;
    const u16* Bu = (job < 8) ? (wut + (size_t)job * 1048576) : wsut;

    int wave = t >> 6, lane = t & 63;
    int ch = (lane & 3) * 8;
    int r0 = (wave * 2 + 0) * 16 + (lane >> 2);
    int r1 = (wave * 2 + 1) * 16 + (lane >> 2);
    int tok0 = tlist[joff + m0 + r0];
    int tok1 = tlist[joff + m0 + r1];
    const u16* a0 = xb + (size_t)tok0 * 1024 + ch;
    const u16* a1 = xb + (size_t)tok1 * 1024 + ch;
    const u16* gB = Bg + (size_t)wave * 8192 + (size_t)(n0 + lane) * 8;
    const u16* uB = Bu + (size_t)wave * 8192 + (size_t)(n0 + lane) * 8;

    int wm = (wave >> 1) << 6, wn = (wave & 1) << 6;
    int quad = lane >> 4, lr = lane & 15;

    f32x4 accg[4][4], accu[4][4];
    f32x4 zz = {0.f, 0.f, 0.f, 0.f};
#pragma unroll
    for (int i = 0; i < 4; i++)
#pragma unroll
        for (int j = 0; j < 4; j++) { accg[i][j] = zz; accu[i][j] = zz; }

#define STAGE1(b_, s_) do { \
        char* bb = smem + (b_) * 24576; \
        u16* As_  = (u16*)bb; \
        u16* Bgs_ = (u16*)(bb + 8192); \
        u16* Bus_ = (u16*)(bb + 16384); \
        int k0_ = (s_) * 32; \
        size_t koff_ = (size_t)k0_ * 1024; \
        GLDS16(a0 + k0_, As_ + (wave * 2 + 0) * 512); \
        GLDS16(a1 + k0_, As_ + (wave * 2 + 1) * 512); \
        GLDS16(gB + koff_,       Bgs_ + wave * 1024); \
        GLDS16(gB + koff_ + 512, Bgs_ + wave * 1024 + 512); \
        GLDS16(uB + koff_,       Bus_ + wave * 1024); \
        GLDS16(uB + koff_ + 512, Bus_ + wave * 1024 + 512); \
    } while (0)

    STAGE1(0, 0);
    __syncthreads();
    for (int s = 0; s < 32; s++) {
        int cur = s & 1;
        if (s < 31) STAGE1(cur ^ 1, s + 1);
        const char* cb = smem + cur * 24576;
        const u16* Asr = (const u16*)cb;
        const u16* Bgr = (const u16*)(cb + 8192);
        const u16* Bur = (const u16*)(cb + 16384);
        short8 af[4], bgf[4], buf[4];
#pragma unroll
        for (int i = 0; i < 4; i++) {
            int nrow = wn + i * 16 + lr;
            af[i]  = *(const short8*)(Asr + (wm + i * 16 + lr) * 32 + quad * 8);
            bgf[i] = *(const short8*)(Bgr + quad * 1024 + nrow * 8);
            buf[i] = *(const short8*)(Bur + quad * 1024 + nrow * 8);
        }
#pragma unroll
        for (int mi = 0; mi < 4; mi++)
#pragma unroll
            for (int ni = 0; ni < 4; ni++) {
                accg[mi][ni] = __builtin_amdgcn_mfma_f32_16x16x32_bf16(af[mi], bgf[ni], accg[mi][ni], 0, 0, 0);
                accu[mi][ni] = __builtin_amdgcn_mfma_f32_16x16x32_bf16(af[mi], buf[ni], accu[mi][ni], 0, 0, 0);
            }
        __syncthreads();
    }
#undef STAGE1
#pragma unroll
    for (int mi = 0; mi < 4; mi++) {
        int rowb = m0 + wm + mi * 16 + quad * 4;
#pragma unroll
        for (int rr = 0; rr < 4; rr++) {
            int row = rowb + rr;
            if (row < jcnt) {
                size_t base = (size_t)(joff + row) * 1024 + n0 + wn;
#pragma unroll
                for (int ni = 0; ni < 4; ni++) {
                    float g = accg[mi][ni][rr];
                    float u = accu[mi][ni][rr];
                    float h = (g / (1.f + expf(-g))) * u;
                    H[base + ni * 16 + lr] = f2bf(h);
                }
            }
        }
    }
}

// ---- GEMM2 job: H @ Wd -> Y bf16 (dbuf) ------------------------------------
__device__ __forceinline__ void gemm2_job(
    int jj, const u16* __restrict__ H, const u16* __restrict__ wdt,
    const u16* __restrict__ wsdt, const int* __restrict__ counts,
    const int* __restrict__ offs, u16* __restrict__ Y, char* smem, int t) {
    int job, mt, nt; gemm_map(jj, job, mt, nt);
    int jcnt = counts[job];
    int m0 = mt << 7;
    if (m0 >= jcnt) return;
    int joff = offs[job];
    int n0 = nt << 7;
    const u16* Bt = (job < 8) ? (wdt + (size_t)job * 1048576) : wsdt;

    int wave = t >> 6, lane = t & 63;
    int ch = (lane & 3) * 8;
    int r0 = (wave * 2 + 0) * 16 + (lane >> 2);
    int r1 = (wave * 2 + 1) * 16 + (lane >> 2);
    const u16* a0 = H + (size_t)(joff + m0 + r0) * 1024 + ch;
    const u16* a1 = H + (size_t)(joff + m0 + r1) * 1024 + ch;
    const u16* bB = Bt + (size_t)wave * 8192 + (size_t)(n0 + lane) * 8;

    int wm = (wave >> 1) << 6, wn = (wave & 1) << 6;
    int quad = lane >> 4, lr = lane & 15;

    f32x4 acc[4][4];
    f32x4 zz = {0.f, 0.f, 0.f, 0.f};
#pragma unroll
    for (int i = 0; i < 4; i++)
#pragma unroll
        for (int j = 0; j < 4; j++) acc[i][j] = zz;

#define STAGE2(b_, s_) do { \
        char* bb = smem + (b_) * 16384; \
        u16* As_ = (u16*)bb; \
        u16* Bs_ = (u16*)(bb + 8192); \
        int k0_ = (s_) * 32; \
        size_t koff_ = (size_t)k0_ * 1024; \
        GLDS16(a0 + k0_, As_ + (wave * 2 + 0) * 512); \
        GLDS16(a1 + k0_, As_ + (wave * 2 + 1) * 512); \
        GLDS16(bB + koff_,       Bs_ + wave * 1024); \
        GLDS16(bB + koff_ + 512, Bs_ + wave * 1024 + 512); \
    } while (0)

    STAGE2(0, 0);
    __syncthreads();
    for (int s = 0; s < 32; s++) {
        int cur = s & 1;
        if (s < 31) STAGE2(cur ^ 1, s + 1);
        const char* cb = smem + cur * 16384;
        const u16* Asr = (const u16*)cb;
        const u16* Bsr = (const u16*)(cb + 8192);
        short8 af[4], bf[4];
#pragma unroll
        for (int i = 0; i < 4; i++) {
            af[i] = *(const short8*)(Asr + (wm + i * 16 + lr) * 32 + quad * 8);
            bf[i] = *(const short8*)(Bsr + quad * 1024 + (wn + i * 16 + lr) * 8);
        }
#pragma unroll
        for (int mi = 0; mi < 4; mi++)
#pragma unroll
            for (int ni = 0; ni < 4; ni++)
                acc[mi][ni] = __builtin_amdgcn_mfma_f32_16x16x32_bf16(af[mi], bf[ni], acc[mi][ni], 0, 0, 0);
        __syncthreads();
    }
#undef STAGE2
#pragma unroll
    for (int mi = 0; mi < 4; mi++) {
        int rowb = m0 + wm + mi * 16 + quad * 4;
#pragma unroll
        for (int rr = 0; rr < 4; rr++) {
            int row = rowb + rr;
            if (row < jcnt) {
                u16* yrow = Y + (size_t)(joff + row) * 1024 + n0 + wn;
#pragma unroll
                for (int ni = 0; ni < 4; ni++)
                    yrow[ni * 16 + lr] = f2bf(acc[mi][ni][rr]);
            }
        }
    }
}

// ---- combine job: out[n] = w0*Y[s0] + w1*Y[s1] + Y[4096+n] -----------------
__device__ __forceinline__ void combine_job(int n, const u16* __restrict__ Y,
                                            const int* __restrict__ slots,
                                            const float* __restrict__ tw,
                                            float* __restrict__ out, int t) {
    int s0 = slots[n * 2], s1 = slots[n * 2 + 1];
    float w0 = tw[n * 2], w1 = tw[n * 2 + 1];
    u16x4 y0 = ((const u16x4*)(Y + (size_t)s0 * 1024))[t];
    u16x4 y1 = ((const u16x4*)(Y + (size_t)s1 * 1024))[t];
    u16x4 ys = ((const u16x4*)(Y + (size_t)(4096 + n) * 1024))[t];
    f32x4 r;
    r.x = w0 * bf2f(y0.x) + w1 * bf2f(y1.x) + bf2f(ys.x);
    r.y = w0 * bf2f(y0.y) + w1 * bf2f(y1.y) + bf2f(ys.y);
    r.z = w0 * bf2f(y0.z) + w1 * bf2f(y1.z) + bf2f(ys.z);
    r.w = w0 * bf2f(y0.w) + w1 * bf2f(y1.w) + bf2f(ys.w);
    ((f32x4*)(out + (size_t)n * 1024))[t] = r;
}

// ================= launch drivers (5 launches) ==============================
__global__ __launch_bounds__(256)
void k_front(const float* __restrict__ wg, const float* __restrict__ wu,
             const float* __restrict__ wsg, const float* __restrict__ wsu,
             u16* __restrict__ wgt, u16* __restrict__ wut,
             u16* __restrict__ wsgt, u16* __restrict__ wsut,
             const float* __restrict__ x, const float* __restrict__ wgate,
             u16* __restrict__ xb, int* __restrict__ tidx, float* __restrict__ tw,
             float* __restrict__ Pp, int* __restrict__ Cp,
             int* __restrict__ tlist, int* __restrict__ curs) {
    __shared__ __attribute__((aligned(128))) char smem[32768];
    int bx = blockIdx.x, t = threadIdx.x;
    if (bx < 512) router_job(bx, x, wgate, xb, tidx, tw, Pp, Cp, tlist, curs, smem, t);
    else          cvt_gu_job(bx - 512, wg, wu, wsg, wsu, wgt, wut, wsgt, wsut, smem, t);
}

__global__ void k_scatter(const int* __restrict__ tidx, const float* __restrict__ Pp,
                          const int* __restrict__ Cp, int* __restrict__ curs,
                          int* __restrict__ tlist, int* __restrict__ slots,
                          float* __restrict__ out, int* __restrict__ counts,
                          int* __restrict__ offs) {
    __shared__ __attribute__((aligned(128))) char smem[4096];
    scatter_job(blockIdx.x, tidx, Pp, Cp, curs, tlist, slots, out, counts, offs,
                smem, threadIdx.x);
}

// gemm jobs FIRST (active-first map -> all active tiles start in round 1),
// cvt_d backfills idle CUs after. launch_bounds(256,2): VGPR cap 256 (body
// needs ~170 live incl. 128 acc regs -> (256,3) would spill, see R4 mega).
// Actual residency is LDS-limited: 3 blocks/CU @ 48KB.
__global__ __launch_bounds__(256, 2)
void k_gemm1(const u16* __restrict__ xb, const u16* __restrict__ wgt,
             const u16* __restrict__ wut, const u16* __restrict__ wsgt,
             const u16* __restrict__ wsut, const int* __restrict__ tlist,
             const int* __restrict__ counts, const int* __restrict__ offs,
             u16* __restrict__ H,
             const float* __restrict__ wd, const float* __restrict__ wsd,
             u16* __restrict__ wdt, u16* __restrict__ wsdt) {
    __shared__ __attribute__((aligned(128))) char smem[49152];
    int bx = blockIdx.x, t = threadIdx.x;
    if (bx < 1152) gemm1_job(bx, xb, wgt, wut, wsgt, wsut, tlist, counts, offs, H, smem, t);
    else           cvt_d_job(bx - 1152, wd, wsd, wdt, wsdt, smem, t);
}

__global__ __launch_bounds__(256, 2)
void k_gemm2(const u16* __restrict__ H, const u16* __restrict__ wdt,
             const u16* __restrict__ wsdt, const int* __restrict__ counts,
             const int* __restrict__ offs, u16* __restrict__ Y) {
    __shared__ __attribute__((aligned(128))) char smem[32768];
    gemm2_job(blockIdx.x, H, wdt, wsdt, counts, offs, Y, smem, threadIdx.x);
}

__global__ void k_combine(const u16* __restrict__ Y, const int* __restrict__ slots,
                          const float* __restrict__ tw, float* __restrict__ out) {
    combine_job(blockIdx.x, Y, slots, tw, out, threadIdx.x);
}

extern "C" void kernel_launch(void* const* d_in, const int* in_sizes, int n_in,
                              void* d_out, int out_size, void* d_ws, size_t ws_size,
                              hipStream_t stream) {
    const float* x     = (const float*)d_in[0];
    const float* wgate = (const float*)d_in[1];
    const float* wg    = (const float*)d_in[2];
    const float* wu    = (const float*)d_in[3];
    const float* wd    = (const float*)d_in[4];
    const float* wsg   = (const float*)d_in[5];
    const float* wsu   = (const float*)d_in[6];
    const float* wsd   = (const float*)d_in[7];
    float* out = (float*)d_out;

    char* ws = (char*)d_ws;
    u16*   xb    = (u16*)(ws + 0);           // 4 MB
    u16*   wgt   = (u16*)(ws + 4194304);     // 16 MB
    u16*   wut   = (u16*)(ws + 20971520);    // 16 MB
    u16*   wdt   = (u16*)(ws + 37748736);    // 16 MB
    u16*   wsgt  = (u16*)(ws + 54525952);    // 2 MB
    u16*   wsut  = (u16*)(ws + 56623104);    // 2 MB
    u16*   wsdt  = (u16*)(ws + 58720256);    // 2 MB
    u16*   H     = (u16*)(ws + 60817408);    // 12.58 MB (6144 rows)
    // Y (bf16) overlays wgt (dead after gemm1; gemm2 runs strictly after)
    u16*   Y     = (u16*)(ws + 4194304);
    int*   tidx  = (int*)(ws + 73400320);
    float* tw    = (float*)(ws + 73416704);
    int*   tlist = (int*)(ws + 73433088);
    int*   slots = (int*)(ws + 73457664);
    int*   counts= (int*)(ws + 73474048);
    int*   offs  = (int*)(ws + 73474112);
    int*   curs  = (int*)(ws + 73474176);
    float* Pp    = (float*)(ws + 73474304);  // 512*8 f32 = 16 KB
    int*   Cp    = (int*)(ws + 73490688);    // 512*8 i32 = 16 KB

    k_front<<<2816, 256, 0, stream>>>(wg, wu, wsg, wsu, wgt, wut, wsgt, wsut,
                                      x, wgate, xb, tidx, tw, Pp, Cp, tlist, curs);
    k_scatter<<<8, 256, 0, stream>>>(tidx, Pp, Cp, curs, tlist, slots,
                                     out, counts, offs);
    k_gemm1<<<2304, 256, 0, stream>>>(xb, wgt, wut, wsgt, wsut, tlist, counts, offs,
                                      H, wd, wsd, wdt, wsdt);
    k_gemm2<<<1152, 256, 0, stream>>>(H, wdt, wsdt, counts, offs, Y);
    k_combine<<<2048, 256, 0, stream>>>(Y, slots, tw, out);
}

// Round 7
// 235.768 us; speedup vs baseline: 2.9608x; 1.0175x over previous
//
#include <hip/hip_runtime.h>
#include <math.h>

typedef unsigned short u16;
typedef __attribute__((ext_vector_type(8))) short short8;
typedef __attribute__((ext_vector_type(4))) float f32x4;
typedef __attribute__((ext_vector_type(4))) unsigned short u16x4;
typedef __attribute__((ext_vector_type(8))) unsigned short u16x8;

#define N_TOK 2048
#define DIM 1024
#define OUT_ELEMS 2097152   // N_TOK * DIM

#define GLDS16(gp, lp) __builtin_amdgcn_global_load_lds( \
    (const __attribute__((address_space(1))) unsigned int*)(gp), \
    (__attribute__((address_space(3))) unsigned int*)(lp), 16, 0, 0)

__device__ __forceinline__ u16 f2bf(float f) {
    union { float f; unsigned u; } v; v.f = f;
    unsigned r = (v.u + 0x7FFFu + ((v.u >> 16) & 1u)) >> 16;
    return (u16)r;
}
__device__ __forceinline__ float bf2f(u16 h) {
    union { unsigned u; float f; } v; v.u = ((unsigned)h) << 16;
    return v.f;
}

// ---- cvt (256-thread): fp32 [8][1024] -> bf16 W'[n][8k] (16KB) -------------
__device__ __forceinline__ void cvt_chunk(const float* __restrict__ src,
                                          u16* __restrict__ dst, int chunk,
                                          char* smem, int t) {
    float* tile = (float*)smem;                          // [8][1024] f32 = 32KB
    const char* gsrc = (const char*)(src + (size_t)chunk * 8192);
    u16* dchunk = dst + (size_t)chunk * 8192;
    int w = t >> 6, l = t & 63;
#pragma unroll
    for (int j = 0; j < 8; j++) {
        int idx = w * 8 + j;                             // 1KB unit, 0..31
        GLDS16(gsrc + idx * 1024 + l * 16, smem + idx * 1024);
    }
    __syncthreads();
    int n0 = (t & 63) * 4 + (t >> 6) * 256;
    f32x4 v[8];
#pragma unroll
    for (int k = 0; k < 8; k++)
        v[k] = *(const f32x4*)(tile + k * 1024 + n0);
#pragma unroll
    for (int i = 0; i < 4; i++) {
        u16x8 o;
#pragma unroll
        for (int k = 0; k < 8; k++) o[k] = f2bf(v[k][i]);
        *(u16x8*)(dchunk + (size_t)(n0 + i) * 8) = o;
    }
}

// ---- cvt (512-thread variant, used inside 512-thread gemm1 launch) ---------
__device__ __forceinline__ void cvt_chunk512(const float* __restrict__ src,
                                             u16* __restrict__ dst, int chunk,
                                             char* smem, int t) {
    float* tile = (float*)smem;
    const char* gsrc = (const char*)(src + (size_t)chunk * 8192);
    u16* dchunk = dst + (size_t)chunk * 8192;
    int w = t >> 6, l = t & 63;
#pragma unroll
    for (int j = 0; j < 4; j++) {
        int idx = w * 4 + j;                             // 1KB unit, 0..31
        GLDS16(gsrc + idx * 1024 + l * 16, smem + idx * 1024);
    }
    __syncthreads();
    int n0 = (t & 63) * 2 + (t >> 6) * 128;              // 2 consecutive n
    float2 v[8];
#pragma unroll
    for (int k = 0; k < 8; k++)
        v[k] = *(const float2*)(tile + k * 1024 + n0);
#pragma unroll
    for (int i = 0; i < 2; i++) {
        u16x8 o;
#pragma unroll
        for (int k = 0; k < 8; k++) o[k] = f2bf(i ? v[k].y : v[k].x);
        *(u16x8*)(dchunk + (size_t)(n0 + i) * 8) = o;
    }
}

__device__ __forceinline__ void cvt_gu_job(int j, const float* wg, const float* wu,
                                           const float* wsg, const float* wsu,
                                           u16* wgt, u16* wut, u16* wsgt, u16* wsut,
                                           char* smem, int t) {
    int mat = j >> 7, chunk = j & 127;
    const float* src; u16* dst;
    if      (mat <  8) { src = wg + (size_t)mat * 1048576;       dst = wgt + (size_t)mat * 1048576; }
    else if (mat < 16) { src = wu + (size_t)(mat - 8) * 1048576; dst = wut + (size_t)(mat - 8) * 1048576; }
    else if (mat == 16){ src = wsg; dst = wsgt; }
    else               { src = wsu; dst = wsut; }
    cvt_chunk(src, dst, chunk, smem, t);
}

__device__ __forceinline__ void cvt_d_job512(int j, const float* wd, const float* wsd,
                                             u16* wdt, u16* wsdt, char* smem, int t) {
    int mat = j >> 7, chunk = j & 127;
    const float* src = (mat < 8) ? (wd + (size_t)mat * 1048576) : wsd;
    u16* dst = (mat < 8) ? (wdt + (size_t)mat * 1048576) : wsdt;
    cvt_chunk512(src, dst, chunk, smem, t);
}

// ---- router: block-job b handles tokens 4b..4b+3, one per wave ------------
__device__ __forceinline__ void router_job(int b, const float* x, const float* wgate,
                                           u16* xb, int* tidx, float* tw,
                                           float* Pp, int* Cp, int* tlist,
                                           int* curs, char* smem, int t) {
    float* sP = (float*)smem;
    int*   sC = (int*)(smem + 64);
    if (t < 8) { sP[t] = 0.f; sC[t] = 0; }
    if (b == 0 && t < 16) curs[t] = 0;
    __syncthreads();
    int wave = t >> 6;
    int lane = t & 63;
    int n = b * 4 + wave;
    const float* xr = x + (size_t)n * DIM;
    u16* xbr = xb + (size_t)n * DIM;
    float acc[8] = {0.f,0.f,0.f,0.f,0.f,0.f,0.f,0.f};
#pragma unroll
    for (int i = 0; i < 16; i++) {
        int d = lane + i * 64;
        float xv = xr[d];
        xbr[d] = f2bf(xv);
        const float* wr = wgate + d * 8;
#pragma unroll
        for (int e = 0; e < 8; e++) acc[e] += xv * wr[e];
    }
#pragma unroll
    for (int off = 32; off; off >>= 1) {
#pragma unroll
        for (int e = 0; e < 8; e++) acc[e] += __shfl_xor(acc[e], off);
    }
    if (lane == 0) {
        tlist[4096 + n] = n;
        float mx = acc[0];
#pragma unroll
        for (int e = 1; e < 8; e++) mx = fmaxf(mx, acc[e]);
        float p[8], s = 0.f;
#pragma unroll
        for (int e = 0; e < 8; e++) { p[e] = expf(acc[e] - mx); s += p[e]; }
        float inv = 1.f / s;
#pragma unroll
        for (int e = 0; e < 8; e++) atomicAdd(&sP[e], p[e] * inv);
        int i0 = 0; float b0 = acc[0];
#pragma unroll
        for (int e = 1; e < 8; e++) if (acc[e] > b0) { b0 = acc[e]; i0 = e; }
        int i1 = -1; float b1 = -3.4e38f;
#pragma unroll
        for (int e = 0; e < 8; e++) if (e != i0 && acc[e] > b1) { b1 = acc[e]; i1 = e; }
        float w0 = 1.f / (1.f + expf(b1 - b0));
        tidx[n * 2] = i0; tidx[n * 2 + 1] = i1;
        tw[n * 2] = w0;   tw[n * 2 + 1] = 1.f - w0;
        atomicAdd(&sC[i0], 1);
        atomicAdd(&sC[i1], 1);
    }
    __syncthreads();
    if (t < 8) { Pp[b * 8 + t] = sP[t]; Cp[b * 8 + t] = sC[t]; }
}

// ---- scatter: reduce partials, aux loss, offs, slot assignment -------------
__device__ __forceinline__ void scatter_job(int bid, const int* tidx, const float* Pp,
                                            const int* Cp, int* curs, int* tlist,
                                            int* slots, float* out, int* counts,
                                            int* offs, char* smem, int t) {
    int*   s_off = (int*)smem;
    int*   sCnt  = (int*)(smem + 32);
    float* sPs   = (float*)(smem + 64);
    int*   redC  = (int*)(smem + 128);
    float* redP  = (float*)(smem + 1152);
    int e = t & 7, g = t >> 3;
    int cs = 0; float ps = 0.f;
#pragma unroll
    for (int j = 0; j < 16; j++) {
        int b = g + j * 32;
        cs += Cp[b * 8 + e];
        ps += Pp[b * 8 + e];
    }
    redC[t] = cs; redP[t] = ps;
    __syncthreads();
    if (t < 8) {
        int c = 0; float p = 0.f;
        for (int g2 = 0; g2 < 32; g2++) { c += redC[g2 * 8 + t]; p += redP[g2 * 8 + t]; }
        sCnt[t] = c; sPs[t] = p;
    }
    __syncthreads();
    if (t == 0) {
        int o = 0;
        for (int e2 = 0; e2 < 8; e2++) { s_off[e2] = o; o += sCnt[e2]; }
    }
    __syncthreads();
    if (bid == 0 && t == 0) {
        float aux = 0.f;
        for (int e2 = 0; e2 < 8; e2++) {
            aux += (float)sCnt[e2] * sPs[e2];
            offs[e2] = s_off[e2]; counts[e2] = sCnt[e2];
        }
        out[OUT_ELEMS] = 8.f * aux / ((float)N_TOK * (float)N_TOK);
        offs[8] = 4096; counts[8] = 2048;
    }
    int n = bid * 256 + t;
    if (n < N_TOK) {
#pragma unroll
        for (int k = 0; k < 2; k++) {
            int ee = tidx[n * 2 + k];
            int p = atomicAdd(&curs[ee], 1);
            int sl = s_off[ee] + p;
            tlist[sl] = n;
            slots[n * 2 + k] = sl;
        }
    }
}

// ---- gemm job mapping: shared-expert tiles first, then routed --------------
__device__ __forceinline__ void gemm_map(int jj, int& job, int& mt, int& nt) {
    if (jj < 128) { job = 8; mt = jj >> 3; nt = jj & 7; }
    else {
        int r = jj - 128;
        mt = r >> 6;
        int rem = r & 63;
        job = rem >> 3;
        nt = rem & 7;
    }
}

// ---- GEMM1 job (512 thr, 8 waves 4Mx2N, wave=32x64): silu(g)*u -> H --------
__device__ __forceinline__ void gemm1_job(
    int jj, const u16* __restrict__ xb, const u16* __restrict__ wgt,
    const u16* __restrict__ wut, const u16* __restrict__ wsgt,
    const u16* __restrict__ wsut, const int* __restrict__ tlist,
    const int* __restrict__ counts, const int* __restrict__ offs,
    u16* __restrict__ H, char* smem, int t) {
    int job, mt, nt; gemm_map(jj, job, mt, nt);
    int jcnt = counts[job];
    int m0 = mt << 7;
    if (m0 >= jcnt) return;                              // block-uniform
    int joff = offs[job];
    int n0 = nt << 7;
    const u16* Bg = (job < 8) ? (wgt + (size_t)job * 1048576) : wsgt;
    const u16* Bu = (job < 8) ? (wut + (size_t)job * 1048576) : wsut;

    int wave = t >> 6, lane = t & 63;
    // A-stage: wave w covers rows 16w..16w+15; lane l -> row +l>>2, 16B chunk l&3
    int arow = wave * 16 + (lane >> 2);
    int tok = tlist[joff + m0 + arow];
    const u16* aA = xb + (size_t)tok * 1024 + (lane & 3) * 8;
    // B-stage: waves 0-3 -> Bg chunk w; waves 4-7 -> Bu chunk w-4; 2 halves (n, n+64)
    int cwv = wave & 3;
    const u16* pB = ((wave < 4) ? Bg : Bu) + (size_t)cwv * 8192
                  + (size_t)(n0 + lane) * 8;
    int bOff = ((wave < 4) ? 8192 : 16384) + cwv * 2048; // LDS byte offset of chunk

    int wm = (wave >> 1) << 5;   // wave row: 0/32/64/96
    int wn = (wave & 1) << 6;    // wave col: 0/64
    int quad = lane >> 4, lr = lane & 15;

    f32x4 accg[2][4], accu[2][4];
    f32x4 zz = {0.f, 0.f, 0.f, 0.f};
#pragma unroll
    for (int i = 0; i < 2; i++)
#pragma unroll
        for (int j = 0; j < 4; j++) { accg[i][j] = zz; accu[i][j] = zz; }

    // stage k-step s into buffer b: 3 GLDS16/thread (A:1, B:2)
#define STAGE1(b_, s_) do { \
        char* bb = smem + (b_) * 24576; \
        int k0_ = (s_) * 32; \
        size_t koff_ = (size_t)k0_ * 1024; \
        GLDS16(aA + k0_, (u16*)bb + wave * 512); \
        GLDS16(pB + koff_,       (u16*)(bb + bOff)); \
        GLDS16(pB + koff_ + 512, (u16*)(bb + bOff + 1024)); \
    } while (0)

    STAGE1(0, 0);
    __syncthreads();
    for (int s = 0; s < 32; s++) {
        int cur = s & 1;
        if (s < 31) STAGE1(cur ^ 1, s + 1);
        const char* cb = smem + cur * 24576;
        const u16* Asr = (const u16*)cb;
        const u16* Bgr = (const u16*)(cb + 8192);
        const u16* Bur = (const u16*)(cb + 16384);
        short8 af[2], bgf[4], buf[4];
#pragma unroll
        for (int i = 0; i < 2; i++)
            af[i] = *(const short8*)(Asr + (wm + i * 16 + lr) * 32 + quad * 8);
#pragma unroll
        for (int i = 0; i < 4; i++) {
            int nrow = wn + i * 16 + lr;
            bgf[i] = *(const short8*)(Bgr + quad * 1024 + nrow * 8);
            buf[i] = *(const short8*)(Bur + quad * 1024 + nrow * 8);
        }
#pragma unroll
        for (int mi = 0; mi < 2; mi++)
#pragma unroll
            for (int ni = 0; ni < 4; ni++) {
                accg[mi][ni] = __builtin_amdgcn_mfma_f32_16x16x32_bf16(af[mi], bgf[ni], accg[mi][ni], 0, 0, 0);
                accu[mi][ni] = __builtin_amdgcn_mfma_f32_16x16x32_bf16(af[mi], buf[ni], accu[mi][ni], 0, 0, 0);
            }
        __syncthreads();
    }
#undef STAGE1
#pragma unroll
    for (int mi = 0; mi < 2; mi++) {
        int rowb = m0 + wm + mi * 16 + quad * 4;
#pragma unroll
        for (int rr = 0; rr < 4; rr++) {
            int row = rowb + rr;
            if (row < jcnt) {
                size_t base = (size_t)(joff + row) * 1024 + n0 + wn;
#pragma unroll
                for (int ni = 0; ni < 4; ni++) {
                    float g = accg[mi][ni][rr];
                    float u = accu[mi][ni][rr];
                    float h = (g / (1.f + expf(-g))) * u;
                    H[base + ni * 16 + lr] = f2bf(h);
                }
            }
        }
    }
}

// ---- GEMM2 job (512 thr, 8 waves): H @ Wd -> Y bf16 ------------------------
__device__ __forceinline__ void gemm2_job(
    int jj, const u16* __restrict__ H, const u16* __restrict__ wdt,
    const u16* __restrict__ wsdt, const int* __restrict__ counts,
    const int* __restrict__ offs, u16* __restrict__ Y, char* smem, int t) {
    int job, mt, nt; gemm_map(jj, job, mt, nt);
    int jcnt = counts[job];
    int m0 = mt << 7;
    if (m0 >= jcnt) return;
    int joff = offs[job];
    int n0 = nt << 7;
    const u16* Bt = (job < 8) ? (wdt + (size_t)job * 1048576) : wsdt;

    int wave = t >> 6, lane = t & 63;
    int arow = wave * 16 + (lane >> 2);
    const u16* aA = H + (size_t)(joff + m0 + arow) * 1024 + (lane & 3) * 8;
    // B-stage: wave w -> chunk w>>1, half w&1 (n = half*64+lane); 1 load/thread
    int cwv = wave >> 1, half = wave & 1;
    const u16* pB = Bt + (size_t)cwv * 8192 + (size_t)(n0 + half * 64 + lane) * 8;
    int bOff = 8192 + cwv * 2048 + half * 1024;

    int wm = (wave >> 1) << 5;
    int wn = (wave & 1) << 6;
    int quad = lane >> 4, lr = lane & 15;

    f32x4 acc[2][4];
    f32x4 zz = {0.f, 0.f, 0.f, 0.f};
#pragma unroll
    for (int i = 0; i < 2; i++)
#pragma unroll
        for (int j = 0; j < 4; j++) acc[i][j] = zz;

#define STAGE2(b_, s_) do { \
        char* bb = smem + (b_) * 16384; \
        int k0_ = (s_) * 32; \
        size_t koff_ = (size_t)k0_ * 1024; \
        GLDS16(aA + k0_, (u16*)bb + wave * 512); \
        GLDS16(pB + koff_, (u16*)(bb + bOff)); \
    } while (0)

    STAGE2(0, 0);
    __syncthreads();
    for (int s = 0; s < 32; s++) {
        int cur = s & 1;
        if (s < 31) STAGE2(cur ^ 1, s + 1);
        const char* cb = smem + cur * 16384;
        const u16* Asr = (const u16*)cb;
        const u16* Bsr = (const u16*)(cb + 8192);
        short8 af[2], bf[4];
#pragma unroll
        for (int i = 0; i < 2; i++)
            af[i] = *(const short8*)(Asr + (wm + i * 16 + lr) * 32 + quad * 8);
#pragma unroll
        for (int i = 0; i < 4; i++)
            bf[i] = *(const short8*)(Bsr + quad * 1024 + (wn + i * 16 + lr) * 8);
#pragma unroll
        for (int mi = 0; mi < 2; mi++)
#pragma unroll
            for (int ni = 0; ni < 4; ni++)
                acc[mi][ni] = __builtin_amdgcn_mfma_f32_16x16x32_bf16(af[mi], bf[ni], acc[mi][ni], 0, 0, 0);
        __syncthreads();
    }
#undef STAGE2
#pragma unroll
    for (int mi = 0; mi < 2; mi++) {
        int rowb = m0 + wm + mi * 16 + quad * 4;
#pragma unroll
        for (int rr = 0; rr < 4; rr++) {
            int row = rowb + rr;
            if (row < jcnt) {
                u16* yrow = Y + (size_t)(joff + row) * 1024 + n0 + wn;
#pragma unroll
                for (int ni = 0; ni < 4; ni++)
                    yrow[ni * 16 + lr] = f2bf(acc[mi][ni][rr]);
            }
        }
    }
}

// ---- combine job -----------------------------------------------------------
__device__ __forceinline__ void combine_job(int n, const u16* __restrict__ Y,
                                            const int* __restrict__ slots,
                                            const float* __restrict__ tw,
                                            float* __restrict__ out, int t) {
    int s0 = slots[n * 2], s1 = slots[n * 2 + 1];
    float w0 = tw[n * 2], w1 = tw[n * 2 + 1];
    u16x4 y0 = ((const u16x4*)(Y + (size_t)s0 * 1024))[t];
    u16x4 y1 = ((const u16x4*)(Y + (size_t)s1 * 1024))[t];
    u16x4 ys = ((const u16x4*)(Y + (size_t)(4096 + n) * 1024))[t];
    f32x4 r;
    r.x = w0 * bf2f(y0.x) + w1 * bf2f(y1.x) + bf2f(ys.x);
    r.y = w0 * bf2f(y0.y) + w1 * bf2f(y1.y) + bf2f(ys.y);
    r.z = w0 * bf2f(y0.z) + w1 * bf2f(y1.z) + bf2f(ys.z);
    r.w = w0 * bf2f(y0.w) + w1 * bf2f(y1.w) + bf2f(ys.w);
    ((f32x4*)(out + (size_t)n * 1024))[t] = r;
}

// ================= launch drivers ===========================================
__global__ __launch_bounds__(256)
void k_front(const float* __restrict__ wg, const float* __restrict__ wu,
             const float* __restrict__ wsg, const float* __restrict__ wsu,
             u16* __restrict__ wgt, u16* __restrict__ wut,
             u16* __restrict__ wsgt, u16* __restrict__ wsut,
             const float* __restrict__ x, const float* __restrict__ wgate,
             u16* __restrict__ xb, int* __restrict__ tidx, float* __restrict__ tw,
             float* __restrict__ Pp, int* __restrict__ Cp,
             int* __restrict__ tlist, int* __restrict__ curs) {
    __shared__ __attribute__((aligned(128))) char smem[32768];
    int bx = blockIdx.x, t = threadIdx.x;
    if (bx < 512) router_job(bx, x, wgate, xb, tidx, tw, Pp, Cp, tlist, curs, smem, t);
    else          cvt_gu_job(bx - 512, wg, wu, wsg, wsu, wgt, wut, wsgt, wsut, smem, t);
}

__global__ void k_scatter(const int* __restrict__ tidx, const float* __restrict__ Pp,
                          const int* __restrict__ Cp, int* __restrict__ curs,
                          int* __restrict__ tlist, int* __restrict__ slots,
                          float* __restrict__ out, int* __restrict__ counts,
                          int* __restrict__ offs) {
    __shared__ __attribute__((aligned(128))) char smem[4096];
    scatter_job(blockIdx.x, tidx, Pp, Cp, curs, tlist, slots, out, counts, offs,
                smem, threadIdx.x);
}

// 512-thread blocks: gemm jobs first (active tiles start round 1), cvt_d
// backfills. launch_bounds(512,2): VGPR cap 256 >> ~124 used, no spill.
__global__ __launch_bounds__(512, 2)
void k_gemm1(const u16* __restrict__ xb, const u16* __restrict__ wgt,
             const u16* __restrict__ wut, const u16* __restrict__ wsgt,
             const u16* __restrict__ wsut, const int* __restrict__ tlist,
             const int* __restrict__ counts, const int* __restrict__ offs,
             u16* __restrict__ H,
             const float* __restrict__ wd, const float* __restrict__ wsd,
             u16* __restrict__ wdt, u16* __restrict__ wsdt) {
    __shared__ __attribute__((aligned(128))) char smem[49152];
    int bx = blockIdx.x, t = threadIdx.x;
    if (bx < 1152) gemm1_job(bx, xb, wgt, wut, wsgt, wsut, tlist, counts, offs, H, smem, t);
    else           cvt_d_job512(bx - 1152, wd, wsd, wdt, wsdt, smem, t);
}

__global__ __launch_bounds__(512, 2)
void k_gemm2(const u16* __restrict__ H, const u16* __restrict__ wdt,
             const u16* __restrict__ wsdt, const int* __restrict__ counts,
             const int* __restrict__ offs, u16* __restrict__ Y) {
    __shared__ __attribute__((aligned(128))) char smem[32768];
    gemm2_job(blockIdx.x, H, wdt, wsdt, counts, offs, Y, smem, threadIdx.x);
}

__global__ void k_combine(const u16* __restrict__ Y, const int* __restrict__ slots,
                          const float* __restrict__ tw, float* __restrict__ out) {
    combine_job(blockIdx.x, Y, slots, tw, out, threadIdx.x);
}

extern "C" void kernel_launch(void* const* d_in, const int* in_sizes, int n_in,
                              void* d_out, int out_size, void* d_ws, size_t ws_size,
                              hipStream_t stream) {
    const float* x     = (const float*)d_in[0];
    const float* wgate = (const float*)d_in[1];
    const float* wg    = (const float*)d_in[2];
    const float* wu    = (const float*)d_in[3];
    const float* wd    = (const float*)d_in[4];
    const float* wsg   = (const float*)d_in[5];
    const float* wsu   = (const float*)d_in[6];
    const float* wsd   = (const float*)d_in[7];
    float* out = (float*)d_out;

    char* ws = (char*)d_ws;
    u16*   xb    = (u16*)(ws + 0);           // 4 MB
    u16*   wgt   = (u16*)(ws + 4194304);     // 16 MB
    u16*   wut   = (u16*)(ws + 20971520);    // 16 MB
    u16*   wdt   = (u16*)(ws + 37748736);    // 16 MB
    u16*   wsgt  = (u16*)(ws + 54525952);    // 2 MB
    u16*   wsut  = (u16*)(ws + 56623104);    // 2 MB
    u16*   wsdt  = (u16*)(ws + 58720256);    // 2 MB
    u16*   H     = (u16*)(ws + 60817408);    // 12.58 MB (6144 rows)
    // Y (bf16) overlays wgt (dead after gemm1; gemm2 runs strictly after)
    u16*   Y     = (u16*)(ws + 4194304);
    int*   tidx  = (int*)(ws + 73400320);
    float* tw    = (float*)(ws + 73416704);
    int*   tlist = (int*)(ws + 73433088);
    int*   slots = (int*)(ws + 73457664);
    int*   counts= (int*)(ws + 73474048);
    int*   offs  = (int*)(ws + 73474112);
    int*   curs  = (int*)(ws + 73474176);
    float* Pp    = (float*)(ws + 73474304);  // 512*8 f32 = 16 KB
    int*   Cp    = (int*)(ws + 73490688);    // 512*8 i32 = 16 KB

    k_front<<<2816, 256, 0, stream>>>(wg, wu, wsg, wsu, wgt, wut, wsgt, wsut,
                                      x, wgate, xb, tidx, tw, Pp, Cp, tlist, curs);
    k_scatter<<<8, 256, 0, stream>>>(tidx, Pp, Cp, curs, tlist, slots,
                                     out, counts, offs);
    k_gemm1<<<2304, 512, 0, stream>>>(xb, wgt, wut, wsgt, wsut, tlist, counts, offs,
                                      H, wd, wsd, wdt, wsdt);
    k_gemm2<<<1152, 512, 0, stream>>>(H, wdt, wsdt, counts, offs, Y);
    k_combine<<<2048, 256, 0, stream>>>(Y, slots, tw, out);
}

// Round 8
// 231.430 us; speedup vs baseline: 3.0163x; 1.0187x over previous
//
#include <hip/hip_runtime.h>
#include <math.h>

typedef unsigned short u16;
typedef __attribute__((ext_vector_type(8))) short short8;
typedef __attribute__((ext_vector_type(4))) float f32x4;
typedef __attribute__((ext_vector_type(4))) unsigned short u16x4;
typedef __attribute__((ext_vector_type(8))) unsigned short u16x8;

#define N_TOK 2048
#define DIM 1024
#define OUT_ELEMS 2097152   // N_TOK * DIM

#define GLDS16(gp, lp) __builtin_amdgcn_global_load_lds( \
    (const __attribute__((address_space(1))) unsigned int*)(gp), \
    (__attribute__((address_space(3))) unsigned int*)(lp), 16, 0, 0)

// counted-vmcnt + raw barrier (T4). sched_barrier pins code motion (rule #18).
#define WAITV_N(n) do { \
    asm volatile("s_waitcnt vmcnt(" #n ")" ::: "memory"); \
    __builtin_amdgcn_sched_barrier(0); \
    __builtin_amdgcn_s_barrier(); \
    __builtin_amdgcn_sched_barrier(0); \
} while (0)

__device__ __forceinline__ u16 f2bf(float f) {
    union { float f; unsigned u; } v; v.f = f;
    unsigned r = (v.u + 0x7FFFu + ((v.u >> 16) & 1u)) >> 16;
    return (u16)r;
}
__device__ __forceinline__ float bf2f(u16 h) {
    union { unsigned u; float f; } v; v.u = ((unsigned)h) << 16;
    return v.f;
}

// ---- cvt (256-thread): fp32 [8][1024] -> bf16 W'[n][8k] (16KB) -------------
__device__ __forceinline__ void cvt_chunk(const float* __restrict__ src,
                                          u16* __restrict__ dst, int chunk,
                                          char* smem, int t) {
    float* tile = (float*)smem;                          // [8][1024] f32 = 32KB
    const char* gsrc = (const char*)(src + (size_t)chunk * 8192);
    u16* dchunk = dst + (size_t)chunk * 8192;
    int w = t >> 6, l = t & 63;
#pragma unroll
    for (int j = 0; j < 8; j++) {
        int idx = w * 8 + j;                             // 1KB unit, 0..31
        GLDS16(gsrc + idx * 1024 + l * 16, smem + idx * 1024);
    }
    __syncthreads();
    int n0 = (t & 63) * 4 + (t >> 6) * 256;
    f32x4 v[8];
#pragma unroll
    for (int k = 0; k < 8; k++)
        v[k] = *(const f32x4*)(tile + k * 1024 + n0);
#pragma unroll
    for (int i = 0; i < 4; i++) {
        u16x8 o;
#pragma unroll
        for (int k = 0; k < 8; k++) o[k] = f2bf(v[k][i]);
        *(u16x8*)(dchunk + (size_t)(n0 + i) * 8) = o;
    }
}

// ---- cvt (512-thread variant) ----------------------------------------------
__device__ __forceinline__ void cvt_chunk512(const float* __restrict__ src,
                                             u16* __restrict__ dst, int chunk,
                                             char* smem, int t) {
    float* tile = (float*)smem;
    const char* gsrc = (const char*)(src + (size_t)chunk * 8192);
    u16* dchunk = dst + (size_t)chunk * 8192;
    int w = t >> 6, l = t & 63;
#pragma unroll
    for (int j = 0; j < 4; j++) {
        int idx = w * 4 + j;                             // 1KB unit, 0..31
        GLDS16(gsrc + idx * 1024 + l * 16, smem + idx * 1024);
    }
    __syncthreads();
    int n0 = (t & 63) * 2 + (t >> 6) * 128;
    float2 v[8];
#pragma unroll
    for (int k = 0; k < 8; k++)
        v[k] = *(const float2*)(tile + k * 1024 + n0);
#pragma unroll
    for (int i = 0; i < 2; i++) {
        u16x8 o;
#pragma unroll
        for (int k = 0; k < 8; k++) o[k] = f2bf(i ? v[k].y : v[k].x);
        *(u16x8*)(dchunk + (size_t)(n0 + i) * 8) = o;
    }
}

__device__ __forceinline__ void cvt_gu_job(int j, const float* wg, const float* wu,
                                           const float* wsg, const float* wsu,
                                           u16* wgt, u16* wut, u16* wsgt, u16* wsut,
                                           char* smem, int t) {
    int mat = j >> 7, chunk = j & 127;
    const float* src; u16* dst;
    if      (mat <  8) { src = wg + (size_t)mat * 1048576;       dst = wgt + (size_t)mat * 1048576; }
    else if (mat < 16) { src = wu + (size_t)(mat - 8) * 1048576; dst = wut + (size_t)(mat - 8) * 1048576; }
    else if (mat == 16){ src = wsg; dst = wsgt; }
    else               { src = wsu; dst = wsut; }
    cvt_chunk(src, dst, chunk, smem, t);
}

__device__ __forceinline__ void cvt_d_job512(int j, const float* wd, const float* wsd,
                                             u16* wdt, u16* wsdt, char* smem, int t) {
    int mat = j >> 7, chunk = j & 127;
    const float* src = (mat < 8) ? (wd + (size_t)mat * 1048576) : wsd;
    u16* dst = (mat < 8) ? (wdt + (size_t)mat * 1048576) : wsdt;
    cvt_chunk512(src, dst, chunk, smem, t);
}

// ---- router ----------------------------------------------------------------
__device__ __forceinline__ void router_job(int b, const float* x, const float* wgate,
                                           u16* xb, int* tidx, float* tw,
                                           float* Pp, int* Cp, int* tlist,
                                           int* curs, char* smem, int t) {
    float* sP = (float*)smem;
    int*   sC = (int*)(smem + 64);
    if (t < 8) { sP[t] = 0.f; sC[t] = 0; }
    if (b == 0 && t < 16) curs[t] = 0;
    __syncthreads();
    int wave = t >> 6;
    int lane = t & 63;
    int n = b * 4 + wave;
    const float* xr = x + (size_t)n * DIM;
    u16* xbr = xb + (size_t)n * DIM;
    float acc[8] = {0.f,0.f,0.f,0.f,0.f,0.f,0.f,0.f};
#pragma unroll
    for (int i = 0; i < 16; i++) {
        int d = lane + i * 64;
        float xv = xr[d];
        xbr[d] = f2bf(xv);
        const float* wr = wgate + d * 8;
#pragma unroll
        for (int e = 0; e < 8; e++) acc[e] += xv * wr[e];
    }
#pragma unroll
    for (int off = 32; off; off >>= 1) {
#pragma unroll
        for (int e = 0; e < 8; e++) acc[e] += __shfl_xor(acc[e], off);
    }
    if (lane == 0) {
        tlist[4096 + n] = n;
        float mx = acc[0];
#pragma unroll
        for (int e = 1; e < 8; e++) mx = fmaxf(mx, acc[e]);
        float p[8], s = 0.f;
#pragma unroll
        for (int e = 0; e < 8; e++) { p[e] = expf(acc[e] - mx); s += p[e]; }
        float inv = 1.f / s;
#pragma unroll
        for (int e = 0; e < 8; e++) atomicAdd(&sP[e], p[e] * inv);
        int i0 = 0; float b0 = acc[0];
#pragma unroll
        for (int e = 1; e < 8; e++) if (acc[e] > b0) { b0 = acc[e]; i0 = e; }
        int i1 = -1; float b1 = -3.4e38f;
#pragma unroll
        for (int e = 0; e < 8; e++) if (e != i0 && acc[e] > b1) { b1 = acc[e]; i1 = e; }
        float w0 = 1.f / (1.f + expf(b1 - b0));
        tidx[n * 2] = i0; tidx[n * 2 + 1] = i1;
        tw[n * 2] = w0;   tw[n * 2 + 1] = 1.f - w0;
        atomicAdd(&sC[i0], 1);
        atomicAdd(&sC[i1], 1);
    }
    __syncthreads();
    if (t < 8) { Pp[b * 8 + t] = sP[t]; Cp[b * 8 + t] = sC[t]; }
}

// ---- scatter ----------------------------------------------------------------
__device__ __forceinline__ void scatter_job(int bid, const int* tidx, const float* Pp,
                                            const int* Cp, int* curs, int* tlist,
                                            int* slots, float* out, int* counts,
                                            int* offs, char* smem, int t) {
    int*   s_off = (int*)smem;
    int*   sCnt  = (int*)(smem + 32);
    float* sPs   = (float*)(smem + 64);
    int*   redC  = (int*)(smem + 128);
    float* redP  = (float*)(smem + 1152);
    int e = t & 7, g = t >> 3;
    int cs = 0; float ps = 0.f;
#pragma unroll
    for (int j = 0; j < 16; j++) {
        int b = g + j * 32;
        cs += Cp[b * 8 + e];
        ps += Pp[b * 8 + e];
    }
    redC[t] = cs; redP[t] = ps;
    __syncthreads();
    if (t < 8) {
        int c = 0; float p = 0.f;
        for (int g2 = 0; g2 < 32; g2++) { c += redC[g2 * 8 + t]; p += redP[g2 * 8 + t]; }
        sCnt[t] = c; sPs[t] = p;
    }
    __syncthreads();
    if (t == 0) {
        int o = 0;
        for (int e2 = 0; e2 < 8; e2++) { s_off[e2] = o; o += sCnt[e2]; }
    }
    __syncthreads();
    if (bid == 0 && t == 0) {
        float aux = 0.f;
        for (int e2 = 0; e2 < 8; e2++) {
            aux += (float)sCnt[e2] * sPs[e2];
            offs[e2] = s_off[e2]; counts[e2] = sCnt[e2];
        }
        out[OUT_ELEMS] = 8.f * aux / ((float)N_TOK * (float)N_TOK);
        offs[8] = 4096; counts[8] = 2048;
    }
    int n = bid * 256 + t;
    if (n < N_TOK) {
#pragma unroll
        for (int k = 0; k < 2; k++) {
            int ee = tidx[n * 2 + k];
            int p = atomicAdd(&curs[ee], 1);
            int sl = s_off[ee] + p;
            tlist[sl] = n;
            slots[n * 2 + k] = sl;
        }
    }
}

// ---- gemm job mapping: shared-expert tiles first, then routed --------------
__device__ __forceinline__ void gemm_map(int jj, int& job, int& mt, int& nt) {
    if (jj < 128) { job = 8; mt = jj >> 3; nt = jj & 7; }
    else {
        int r = jj - 128;
        mt = r >> 6;
        int rem = r & 63;
        job = rem >> 3;
        nt = rem & 7;
    }
}

// ---- GEMM1 job (512 thr, 8 waves, 3-buffer counted-vmcnt pipeline) ---------
__device__ __forceinline__ void gemm1_job(
    int jj, const u16* __restrict__ xb, const u16* __restrict__ wgt,
    const u16* __restrict__ wut, const u16* __restrict__ wsgt,
    const u16* __restrict__ wsut, const int* __restrict__ tlist,
    const int* __restrict__ counts, const int* __restrict__ offs,
    u16* __restrict__ H, char* smem, int t) {
    int job, mt, nt; gemm_map(jj, job, mt, nt);
    int jcnt = counts[job];
    int m0 = mt << 7;
    if (m0 >= jcnt) return;                              // block-uniform
    int joff = offs[job];
    int n0 = nt << 7;
    const u16* Bg = (job < 8) ? (wgt + (size_t)job * 1048576) : wsgt;
    const u16* Bu = (job < 8) ? (wut + (size_t)job * 1048576) : wsut;

    int wave = t >> 6, lane = t & 63;
    int arow = wave * 16 + (lane >> 2);
    int tok = tlist[joff + m0 + arow];
    const u16* aA = xb + (size_t)tok * 1024 + (lane & 3) * 8;
    int cwv = wave & 3;
    const u16* pB = ((wave < 4) ? Bg : Bu) + (size_t)cwv * 8192
                  + (size_t)(n0 + lane) * 8;
    int bOff = ((wave < 4) ? 8192 : 16384) + cwv * 2048;

    int wm = (wave >> 1) << 5;   // wave row: 0/32/64/96
    int wn = (wave & 1) << 6;    // wave col: 0/64
    int quad = lane >> 4, lr = lane & 15;

    f32x4 accg[2][4], accu[2][4];
    f32x4 zz = {0.f, 0.f, 0.f, 0.f};
#pragma unroll
    for (int i = 0; i < 2; i++)
#pragma unroll
        for (int j = 0; j < 4; j++) { accg[i][j] = zz; accu[i][j] = zz; }

    // stage k-step s into buffer b: 3 GLDS16/thread (A:1, B:2)
#define STAGE1(b_, s_) do { \
        char* bb = smem + (b_) * 24576; \
        int k0_ = (s_) * 32; \
        size_t koff_ = (size_t)k0_ * 1024; \
        GLDS16(aA + k0_, (u16*)bb + wave * 512); \
        GLDS16(pB + koff_,       (u16*)(bb + bOff)); \
        GLDS16(pB + koff_ + 512, (u16*)(bb + bOff + 1024)); \
    } while (0)

    STAGE1(0, 0);
    STAGE1(1, 1);
    WAITV_N(3);                              // buf0's 3 loads retired; buf1 in flight
    int cur = 0;
    for (int s = 0; s < 32; s++) {
        if (s < 30) {
            int nb = cur + 2; if (nb >= 3) nb -= 3;
            STAGE1(nb, s + 2);
        }
        const char* cb = smem + cur * 24576;
        const u16* Asr = (const u16*)cb;
        const u16* Bgr = (const u16*)(cb + 8192);
        const u16* Bur = (const u16*)(cb + 16384);
        short8 af[2], bgf[4], buf[4];
#pragma unroll
        for (int i = 0; i < 2; i++)
            af[i] = *(const short8*)(Asr + (wm + i * 16 + lr) * 32 + quad * 8);
#pragma unroll
        for (int i = 0; i < 4; i++) {
            int nrow = wn + i * 16 + lr;
            bgf[i] = *(const short8*)(Bgr + quad * 1024 + nrow * 8);
            buf[i] = *(const short8*)(Bur + quad * 1024 + nrow * 8);
        }
#pragma unroll
        for (int mi = 0; mi < 2; mi++)
#pragma unroll
            for (int ni = 0; ni < 4; ni++) {
                accg[mi][ni] = __builtin_amdgcn_mfma_f32_16x16x32_bf16(af[mi], bgf[ni], accg[mi][ni], 0, 0, 0);
                accu[mi][ni] = __builtin_amdgcn_mfma_f32_16x16x32_bf16(af[mi], buf[ni], accu[mi][ni], 0, 0, 0);
            }
        if (s < 31) {                        // next buffer must be resident
            if (s < 30) WAITV_N(3);          // oldest 3 (next buf) done; newest 3 stay
            else        WAITV_N(0);          // last prefetch: drain all
        }
        cur = cur + 1; if (cur >= 3) cur -= 3;
    }
#undef STAGE1
#pragma unroll
    for (int mi = 0; mi < 2; mi++) {
        int rowb = m0 + wm + mi * 16 + quad * 4;
#pragma unroll
        for (int rr = 0; rr < 4; rr++) {
            int row = rowb + rr;
            if (row < jcnt) {
                size_t base = (size_t)(joff + row) * 1024 + n0 + wn;
#pragma unroll
                for (int ni = 0; ni < 4; ni++) {
                    float g = accg[mi][ni][rr];
                    float u = accu[mi][ni][rr];
                    float h = (g / (1.f + expf(-g))) * u;
                    H[base + ni * 16 + lr] = f2bf(h);
                }
            }
        }
    }
}

// ---- GEMM2 job (512 thr, 8 waves, 3-buffer counted-vmcnt pipeline) ---------
__device__ __forceinline__ void gemm2_job(
    int jj, const u16* __restrict__ H, const u16* __restrict__ wdt,
    const u16* __restrict__ wsdt, const int* __restrict__ counts,
    const int* __restrict__ offs, u16* __restrict__ Y, char* smem, int t) {
    int job, mt, nt; gemm_map(jj, job, mt, nt);
    int jcnt = counts[job];
    int m0 = mt << 7;
    if (m0 >= jcnt) return;
    int joff = offs[job];
    int n0 = nt << 7;
    const u16* Bt = (job < 8) ? (wdt + (size_t)job * 1048576) : wsdt;

    int wave = t >> 6, lane = t & 63;
    int arow = wave * 16 + (lane >> 2);
    const u16* aA = H + (size_t)(joff + m0 + arow) * 1024 + (lane & 3) * 8;
    int cwv = wave >> 1, half = wave & 1;
    const u16* pB = Bt + (size_t)cwv * 8192 + (size_t)(n0 + half * 64 + lane) * 8;
    int bOff = 8192 + cwv * 2048 + half * 1024;

    int wm = (wave >> 1) << 5;
    int wn = (wave & 1) << 6;
    int quad = lane >> 4, lr = lane & 15;

    f32x4 acc[2][4];
    f32x4 zz = {0.f, 0.f, 0.f, 0.f};
#pragma unroll
    for (int i = 0; i < 2; i++)
#pragma unroll
        for (int j = 0; j < 4; j++) acc[i][j] = zz;

#define STAGE2(b_, s_) do { \
        char* bb = smem + (b_) * 16384; \
        int k0_ = (s_) * 32; \
        size_t koff_ = (size_t)k0_ * 1024; \
        GLDS16(aA + k0_, (u16*)bb + wave * 512); \
        GLDS16(pB + koff_, (u16*)(bb + bOff)); \
    } while (0)

    STAGE2(0, 0);
    STAGE2(1, 1);
    WAITV_N(2);                              // buf0's 2 loads retired
    int cur = 0;
    for (int s = 0; s < 32; s++) {
        if (s < 30) {
            int nb = cur + 2; if (nb >= 3) nb -= 3;
            STAGE2(nb, s + 2);
        }
        const char* cb = smem + cur * 16384;
        const u16* Asr = (const u16*)cb;
        const u16* Bsr = (const u16*)(cb + 8192);
        short8 af[2], bf[4];
#pragma unroll
        for (int i = 0; i < 2; i++)
            af[i] = *(const short8*)(Asr + (wm + i * 16 + lr) * 32 + quad * 8);
#pragma unroll
        for (int i = 0; i < 4; i++)
            bf[i] = *(const short8*)(Bsr + quad * 1024 + (wn + i * 16 + lr) * 8);
#pragma unroll
        for (int mi = 0; mi < 2; mi++)
#pragma unroll
            for (int ni = 0; ni < 4; ni++)
                acc[mi][ni] = __builtin_amdgcn_mfma_f32_16x16x32_bf16(af[mi], bf[ni], acc[mi][ni], 0, 0, 0);
        if (s < 31) {
            if (s < 30) WAITV_N(2);
            else        WAITV_N(0);
        }
        cur = cur + 1; if (cur >= 3) cur -= 3;
    }
#undef STAGE2
#pragma unroll
    for (int mi = 0; mi < 2; mi++) {
        int rowb = m0 + wm + mi * 16 + quad * 4;
#pragma unroll
        for (int rr = 0; rr < 4; rr++) {
            int row = rowb + rr;
            if (row < jcnt) {
                u16* yrow = Y + (size_t)(joff + row) * 1024 + n0 + wn;
#pragma unroll
                for (int ni = 0; ni < 4; ni++)
                    yrow[ni * 16 + lr] = f2bf(acc[mi][ni][rr]);
            }
        }
    }
}

// ---- combine job -----------------------------------------------------------
__device__ __forceinline__ void combine_job(int n, const u16* __restrict__ Y,
                                            const int* __restrict__ slots,
                                            const float* __restrict__ tw,
                                            float* __restrict__ out, int t) {
    int s0 = slots[n * 2], s1 = slots[n * 2 + 1];
    float w0 = tw[n * 2], w1 = tw[n * 2 + 1];
    u16x4 y0 = ((const u16x4*)(Y + (size_t)s0 * 1024))[t];
    u16x4 y1 = ((const u16x4*)(Y + (size_t)s1 * 1024))[t];
    u16x4 ys = ((const u16x4*)(Y + (size_t)(4096 + n) * 1024))[t];
    f32x4 r;
    r.x = w0 * bf2f(y0.x) + w1 * bf2f(y1.x) + bf2f(ys.x);
    r.y = w0 * bf2f(y0.y) + w1 * bf2f(y1.y) + bf2f(ys.y);
    r.z = w0 * bf2f(y0.z) + w1 * bf2f(y1.z) + bf2f(ys.z);
    r.w = w0 * bf2f(y0.w) + w1 * bf2f(y1.w) + bf2f(ys.w);
    ((f32x4*)(out + (size_t)n * 1024))[t] = r;
}

// ================= launch drivers ===========================================
__global__ __launch_bounds__(256)
void k_front(const float* __restrict__ wg, const float* __restrict__ wu,
             const float* __restrict__ wsg, const float* __restrict__ wsu,
             u16* __restrict__ wgt, u16* __restrict__ wut,
             u16* __restrict__ wsgt, u16* __restrict__ wsut,
             const float* __restrict__ x, const float* __restrict__ wgate,
             u16* __restrict__ xb, int* __restrict__ tidx, float* __restrict__ tw,
             float* __restrict__ Pp, int* __restrict__ Cp,
             int* __restrict__ tlist, int* __restrict__ curs) {
    __shared__ __attribute__((aligned(128))) char smem[32768];
    int bx = blockIdx.x, t = threadIdx.x;
    if (bx < 512) router_job(bx, x, wgate, xb, tidx, tw, Pp, Cp, tlist, curs, smem, t);
    else          cvt_gu_job(bx - 512, wg, wu, wsg, wsu, wgt, wut, wsgt, wsut, smem, t);
}

__global__ void k_scatter(const int* __restrict__ tidx, const float* __restrict__ Pp,
                          const int* __restrict__ Cp, int* __restrict__ curs,
                          int* __restrict__ tlist, int* __restrict__ slots,
                          float* __restrict__ out, int* __restrict__ counts,
                          int* __restrict__ offs) {
    __shared__ __attribute__((aligned(128))) char smem[4096];
    scatter_job(blockIdx.x, tidx, Pp, Cp, curs, tlist, slots, out, counts, offs,
                smem, threadIdx.x);
}

// 512-thread blocks, gemm first, cvt_d backfill. 3-buffer LDS 72KB -> 2/CU.
__global__ __launch_bounds__(512, 2)
void k_gemm1(const u16* __restrict__ xb, const u16* __restrict__ wgt,
             const u16* __restrict__ wut, const u16* __restrict__ wsgt,
             const u16* __restrict__ wsut, const int* __restrict__ tlist,
             const int* __restrict__ counts, const int* __restrict__ offs,
             u16* __restrict__ H,
             const float* __restrict__ wd, const float* __restrict__ wsd,
             u16* __restrict__ wdt, u16* __restrict__ wsdt) {
    __shared__ __attribute__((aligned(128))) char smem[73728];
    int bx = blockIdx.x, t = threadIdx.x;
    if (bx < 1152) gemm1_job(bx, xb, wgt, wut, wsgt, wsut, tlist, counts, offs, H, smem, t);
    else           cvt_d_job512(bx - 1152, wd, wsd, wdt, wsdt, smem, t);
}

__global__ __launch_bounds__(512, 2)
void k_gemm2(const u16* __restrict__ H, const u16* __restrict__ wdt,
             const u16* __restrict__ wsdt, const int* __restrict__ counts,
             const int* __restrict__ offs, u16* __restrict__ Y) {
    __shared__ __attribute__((aligned(128))) char smem[49152];
    gemm2_job(blockIdx.x, H, wdt, wsdt, counts, offs, Y, smem, threadIdx.x);
}

__global__ void k_combine(const u16* __restrict__ Y, const int* __restrict__ slots,
                          const float* __restrict__ tw, float* __restrict__ out) {
    combine_job(blockIdx.x, Y, slots, tw, out, threadIdx.x);
}

extern "C" void kernel_launch(void* const* d_in, const int* in_sizes, int n_in,
                              void* d_out, int out_size, void* d_ws, size_t ws_size,
                              hipStream_t stream) {
    const float* x     = (const float*)d_in[0];
    const float* wgate = (const float*)d_in[1];
    const float* wg    = (const float*)d_in[2];
    const float* wu    = (const float*)d_in[3];
    const float* wd    = (const float*)d_in[4];
    const float* wsg   = (const float*)d_in[5];
    const float* wsu   = (const float*)d_in[6];
    const float* wsd   = (const float*)d_in[7];
    float* out = (float*)d_out;

    char* ws = (char*)d_ws;
    u16*   xb    = (u16*)(ws + 0);           // 4 MB
    u16*   wgt   = (u16*)(ws + 4194304);     // 16 MB
    u16*   wut   = (u16*)(ws + 20971520);    // 16 MB
    u16*   wdt   = (u16*)(ws + 37748736);    // 16 MB
    u16*   wsgt  = (u16*)(ws + 54525952);    // 2 MB
    u16*   wsut  = (u16*)(ws + 56623104);    // 2 MB
    u16*   wsdt  = (u16*)(ws + 58720256);    // 2 MB
    u16*   H     = (u16*)(ws + 60817408);    // 12.58 MB (6144 rows)
    // Y (bf16) overlays wgt (dead after gemm1; gemm2 runs strictly after)
    u16*   Y     = (u16*)(ws + 4194304);
    int*   tidx  = (int*)(ws + 73400320);
    float* tw    = (float*)(ws + 73416704);
    int*   tlist = (int*)(ws + 73433088);
    int*   slots = (int*)(ws + 73457664);
    int*   counts= (int*)(ws + 73474048);
    int*   offs  = (int*)(ws + 73474112);
    int*   curs  = (int*)(ws + 73474176);
    float* Pp    = (float*)(ws + 73474304);  // 512*8 f32 = 16 KB
    int*   Cp    = (int*)(ws + 73490688);    // 512*8 i32 = 16 KB

    k_front<<<2816, 256, 0, stream>>>(wg, wu, wsg, wsu, wgt, wut, wsgt, wsut,
                                      x, wgate, xb, tidx, tw, Pp, Cp, tlist, curs);
    k_scatter<<<8, 256, 0, stream>>>(tidx, Pp, Cp, curs, tlist, slots,
                                     out, counts, offs);
    k_gemm1<<<2304, 512, 0, stream>>>(xb, wgt, wut, wsgt, wsut, tlist, counts, offs,
                                      H, wd, wsd, wdt, wsdt);
    k_gemm2<<<1152, 512, 0, stream>>>(H, wdt, wsdt, counts, offs, Y);
    k_combine<<<2048, 256, 0, stream>>>(Y, slots, tw, out);
}